// Round 11
// baseline (1354.721 us; speedup 1.0000x reference)
//
#include <hip/hip_runtime.h>

#define NN 100000
#define NE 640000
#define OUTF 128
#define K1 100
#define KE 118
#define KPAD 128
#define ASTR 136              // padded LDS row stride (ushorts)
#define ATT_SCALE 0.17677669529663687f
#define NSCANB 391            // ceil(NN/256)

typedef __attribute__((ext_vector_type(8))) short short8;
typedef __attribute__((ext_vector_type(4))) float f32x4;

__device__ __forceinline__ unsigned short f2bf(float f) {
    unsigned u = __float_as_uint(f);
    u += 0x7FFFu + ((u >> 16) & 1u);   // RNE
    return (unsigned short)(u >> 16);
}
__device__ __forceinline__ float bf2f(unsigned short h) {
    return __uint_as_float(((unsigned)h) << 16);
}

// ---------- prep: transposed bf16 weights [col][k]; WmT rows 118-121 = one-hot etype tables ----------
__global__ void prep_weights(
    const float* __restrict__ w1q, const float* __restrict__ w1k,
    const float* __restrict__ w1v, const float* __restrict__ w1s,
    const float* __restrict__ w2q, const float* __restrict__ w2k,
    const float* __restrict__ w2v, const float* __restrict__ w2s,
    const float* __restrict__ we1, const float* __restrict__ we2,
    const float* __restrict__ emb,
    const float* __restrict__ b1q, const float* __restrict__ b1k,
    const float* __restrict__ b1v, const float* __restrict__ b1s,
    const float* __restrict__ b2q, const float* __restrict__ b2k,
    const float* __restrict__ b2v, const float* __restrict__ b2s,
    unsigned short* __restrict__ WT1, unsigned short* __restrict__ WT2,
    unsigned short* __restrict__ WmT1, unsigned short* __restrict__ WmT2,
    float* __restrict__ bias1, float* __restrict__ bias2)
{
    int idx = blockIdx.x * blockDim.x + threadIdx.x;
    int stride = gridDim.x * blockDim.x;
    for (int i = idx; i < 512 * KPAD; i += stride) {
        int col = i >> 7, k = i & 127;
        int which = col >> 7, c = col & 127;
        const float* s1 = (which == 0) ? w1q : (which == 1) ? w1k : (which == 2) ? w1v : w1s;
        const float* s2 = (which == 0) ? w2q : (which == 1) ? w2k : (which == 2) ? w2v : w2s;
        float v1 = (k < K1) ? s1[k * OUTF + c] : 0.f;
        float v2 = s2[k * OUTF + c];
        WT1[i] = f2bf(v1); WT2[i] = f2bf(v2);
    }
    for (int i = idx; i < OUTF * KPAD; i += stride) {
        int col = i >> 7, k = i & 127;
        float v1 = 0.f, v2 = 0.f;
        if (k < 3)                 { v1 = we1[k * OUTF + col];       v2 = we2[k * OUTF + col]; }
        else if (k >= 4 && k < KE) { v1 = we1[(k - 1) * OUTF + col]; v2 = we2[(k - 1) * OUTF + col]; }
        else if (k >= KE && k < KE + 4) {
            int t = k - KE;
            #pragma unroll
            for (int r = 0; r < 8; r++) {
                float ev = emb[t * 8 + r];
                v1 += ev * we1[(117 + r) * OUTF + col];
                v2 += ev * we2[(117 + r) * OUTF + col];
            }
        }
        WmT1[i] = f2bf(v1); WmT2[i] = f2bf(v2);
    }
    for (int i = idx; i < 512; i += stride) {
        int which = i >> 7, c = i & 127;
        const float* sb1 = (which == 0) ? b1q : (which == 1) ? b1k : (which == 2) ? b1v : b1s;
        const float* sb2 = (which == 0) ? b2q : (which == 1) ? b2k : (which == 2) ? b2v : b2s;
        bias1[i] = sb1[c]; bias2[i] = sb2[c];
    }
}

// ---------- once: EA fp32 -> EAb bf16 [E][128], one-hot etype baked; pure streaming ----------
__global__ __launch_bounds__(256) void convert_ea(const float* __restrict__ EA,
                                                  unsigned short* __restrict__ EAb)
{
    int lane = threadIdx.x & 63;
    int gw = (int)((blockIdx.x * (size_t)blockDim.x + threadIdx.x) >> 6);
    int nW = (gridDim.x * blockDim.x) >> 6;
    int k = lane * 2;
    for (int e = gw; e < NE; e += nW) {
        const float* row = EA + (size_t)e * KE;
        float2 v = make_float2(0.f, 0.f);
        if (k < KE) v = *(const float2*)(row + k);
        int et = (int)row[3];                 // broadcast load, L1-served
        if (lane == 1) v.y = 0.f;             // col 3 = etype -> zero
        int oh = KE + et;                     // one-hot col 118..121
        if (k == oh)     v.x = 1.f;
        if (k + 1 == oh) v.y = 1.f;
        unsigned pv = (unsigned)f2bf(v.x) | ((unsigned)f2bf(v.y) << 16);
        *(unsigned*)(EAb + (size_t)e * 128 + k) = pv;
    }
}

// ---------- CSR build ----------
__global__ void hist_kernel(const int* __restrict__ dstI, int* __restrict__ cnt) {
    int e = blockIdx.x * 256 + threadIdx.x;
    if (e < NE) atomicAdd(&cnt[dstI[e]], 1);
}
__global__ void scan1(const int* __restrict__ cnt, int* __restrict__ S1, int* __restrict__ bsum) {
    __shared__ int sd[256];
    int t = blockIdx.x * 256 + threadIdx.x;
    sd[threadIdx.x] = (t < NN) ? cnt[t] : 0;
    __syncthreads();
    for (int off = 1; off < 256; off <<= 1) {
        int x = (threadIdx.x >= off) ? sd[threadIdx.x - off] : 0;
        __syncthreads();
        sd[threadIdx.x] += x;
        __syncthreads();
    }
    if (t < NN) S1[t] = sd[threadIdx.x];
    if (threadIdx.x == 255) bsum[blockIdx.x] = sd[255];
}
__global__ void scan2(const int* __restrict__ bsum, int* __restrict__ boff) {
    __shared__ int sd[512];
    int t = threadIdx.x;
    sd[t] = (t < NSCANB) ? bsum[t] : 0;
    __syncthreads();
    for (int off = 1; off < 512; off <<= 1) {
        int x = (t >= off) ? sd[t - off] : 0;
        __syncthreads();
        sd[t] += x;
        __syncthreads();
    }
    if (t < NSCANB) boff[t] = (t == 0) ? 0 : sd[t - 1];
}
__global__ void scan3(const int* __restrict__ S1, const int* __restrict__ boff,
                      const int* __restrict__ cnt,
                      int* __restrict__ row_start, int* __restrict__ cursor) {
    int t = blockIdx.x * 256 + threadIdx.x;
    if (t < NN) {
        int incl = S1[t] + boff[t >> 8];
        row_start[t + 1] = incl;
        cursor[t] = incl - cnt[t];
        if (t == 0) row_start[0] = 0;
    }
}
__global__ void scatter_csr(const int* __restrict__ srcI, const int* __restrict__ dstI,
                            int* __restrict__ cursor,
                            int* __restrict__ csr_src, int* __restrict__ csr_eid) {
    int e = blockIdx.x * 256 + threadIdx.x;
    if (e < NE) {
        int j = atomicAdd(&cursor[dstI[e]], 1);
        csr_src[j] = srcI[e];
        csr_eid[j] = e;
    }
}

// ---------- node GEMM: Q fp32 (pre-scaled), K/V bf16 packed [K|V], H fp32 ----------
__global__ __launch_bounds__(256) void node_mfma(
    const float* __restrict__ X, int ldx, int Kdim, int relu, int n,
    const unsigned short* __restrict__ WT, const float* __restrict__ bias,
    float* __restrict__ Qp, unsigned short* __restrict__ KVp, float* __restrict__ Hp)
{
    __shared__ unsigned short Alds[128][ASTR];
    int tid = threadIdx.x;
    int rowbase = blockIdx.x * 128;

    for (int idx = tid; idx < 128 * 68; idx += 256) {
        int r = idx / 68, kv = idx % 68;
        int k = kv * 2;
        float2 v = make_float2(0.f, 0.f);
        int gr = rowbase + r;
        if (gr < n && k < Kdim) v = *(const float2*)(X + (size_t)gr * ldx + k);
        if (relu) { v.x = fmaxf(v.x, 0.f); v.y = fmaxf(v.y, 0.f); }
        unsigned pv = (unsigned)f2bf(v.x) | ((unsigned)f2bf(v.y) << 16);
        *(unsigned*)&Alds[r][k] = pv;
    }
    __syncthreads();

    int lane = tid & 63, wid = tid >> 6;
    int wm = wid >> 1, wn = wid & 1;
    int l15 = lane & 15, l4 = lane >> 4;

    for (int nb = 0; nb < 4; nb++) {
        f32x4 acc[4][4];
        #pragma unroll
        for (int mf = 0; mf < 4; mf++)
            #pragma unroll
            for (int nf = 0; nf < 4; nf++)
                acc[mf][nf] = (f32x4){0.f, 0.f, 0.f, 0.f};

        const unsigned short* wbase = WT + (size_t)(nb * 128 + wn * 64 + l15) * KPAD + l4 * 8;
        #pragma unroll
        for (int ks = 0; ks < 4; ks++) {
            short8 af[4], bfr[4];
            #pragma unroll
            for (int mf = 0; mf < 4; mf++)
                af[mf] = *(const short8*)&Alds[wm * 64 + mf * 16 + l15][ks * 32 + l4 * 8];
            #pragma unroll
            for (int nf = 0; nf < 4; nf++)
                bfr[nf] = *(const short8*)(wbase + (size_t)nf * 16 * KPAD + ks * 32);
            #pragma unroll
            for (int mf = 0; mf < 4; mf++)
                #pragma unroll
                for (int nf = 0; nf < 4; nf++)
                    acc[mf][nf] = __builtin_amdgcn_mfma_f32_16x16x32_bf16(af[mf], bfr[nf], acc[mf][nf], 0, 0, 0);
        }

        #pragma unroll
        for (int nf = 0; nf < 4; nf++) {
            int col = wn * 64 + nf * 16 + l15;
            float bv = bias[nb * 128 + col];
            #pragma unroll
            for (int mf = 0; mf < 4; mf++) {
                #pragma unroll
                for (int rr = 0; rr < 4; rr++) {
                    int row = rowbase + wm * 64 + mf * 16 + l4 * 4 + rr;
                    if (row < n) {
                        float val = acc[mf][nf][rr] + bv;
                        if (nb == 0)      Qp[(size_t)row * OUTF + col] = val * ATT_SCALE;
                        else if (nb == 3) Hp[(size_t)row * OUTF + col] = val;
                        else KVp[(size_t)row * 256 + (nb == 1 ? 0 : 128) + col] = f2bf(val);
                    }
                }
            }
        }
    }
}

// ---------- per-layer edge GEMM: barrier-free, A-frags direct from global, linear EE store ----------
// 64-row tile, 256 threads / 4 waves / 16 rows per wave; EEc may alias EAb (wave-private rows,
// A held in registers before any store -> in-place safe)
__global__ __launch_bounds__(256) void edge_mfma_one(
    const unsigned short* __restrict__ EAb,
    const unsigned short* __restrict__ WmT,
    unsigned short* EEc)
{
    __shared__ unsigned short Tlds[64][ASTR];
    int tid = threadIdx.x;
    int lane = tid & 63, w = tid >> 6;
    int e0 = blockIdx.x * 64;
    int l15 = lane & 15, l4 = lane >> 4;
    int rbase = w * 16;

    // A fragments straight from global (16B/lane, L2/L3-friendly streaming)
    short8 af[4];
    #pragma unroll
    for (int ks = 0; ks < 4; ks++)
        af[ks] = *(const short8*)(EAb + (size_t)(e0 + rbase + l15) * 128 + ks * 32 + l4 * 8);

    f32x4 acc[8];
    #pragma unroll
    for (int nf = 0; nf < 8; nf++) acc[nf] = (f32x4){0.f, 0.f, 0.f, 0.f};

    #pragma unroll
    for (int ks = 0; ks < 4; ks++) {
        short8 bfr[8];
        #pragma unroll
        for (int nf = 0; nf < 8; nf++)
            bfr[nf] = *(const short8*)(WmT + (size_t)(nf * 16 + l15) * KPAD + ks * 32 + l4 * 8);
        #pragma unroll
        for (int nf = 0; nf < 8; nf++)
            acc[nf] = __builtin_amdgcn_mfma_f32_16x16x32_bf16(af[ks], bfr[nf], acc[nf], 0, 0, 0);
    }

    // wave-private transpose through own LDS rows (no barrier), then coalesced linear store
    #pragma unroll
    for (int nf = 0; nf < 8; nf++)
        #pragma unroll
        for (int rr = 0; rr < 4; rr++)
            Tlds[rbase + l4 * 4 + rr][nf * 16 + l15] = f2bf(acc[nf][rr]);
    #pragma unroll
    for (int it = 0; it < 4; it++) {
        int t2 = it * 64 + lane;
        int rid = t2 >> 4, c8 = (t2 & 15) * 8;   // rid spans [0,16) over it=0..3
        uint4 v = *(const uint4*)&Tlds[rbase + rid][c8];
        *(uint4*)(EEc + ((size_t)(e0 + rbase + rid)) * 128 + c8) = v;
    }
}

// ---------- fused attn: one wave per dst, online softmax, 1-deep prefetch, EE gathered by eid ----------
__global__ __launch_bounds__(256) void attn_node(
    const float* __restrict__ Qp, const unsigned short* __restrict__ KVp,
    const unsigned short* __restrict__ EEc,
    const int* __restrict__ row_start, const int* __restrict__ csr_src,
    const int* __restrict__ csr_eid,
    const float* __restrict__ Hskip, float* __restrict__ Out)
{
    int lane = threadIdx.x & 63;
    int gw = (int)((blockIdx.x * (size_t)blockDim.x + threadIdx.x) >> 6);
    int nW = (gridDim.x * blockDim.x) >> 6;
    int c2 = lane * 2;

    for (int d = gw; d < NN; d += nW) {
        int rs = row_start[d], re = row_start[d + 1];
        float2 q = *(const float2*)(Qp + (size_t)d * OUTF + c2);
        float m = -3.4e38f, s = 0.f, a0 = 0.f, a1 = 0.f;

        int j0 = (rs < re) ? rs : 0;
        int sj = csr_src[j0];
        int ej = csr_eid[j0];
        unsigned kc = *(const unsigned*)(KVp + (size_t)sj * 256 + c2);
        unsigned vc = *(const unsigned*)(KVp + (size_t)sj * 256 + 128 + c2);
        unsigned ec = *(const unsigned*)(EEc + (size_t)ej * 128 + c2);

        for (int j = rs; j < re; j++) {
            int jn = (j + 1 < re) ? j + 1 : j;
            int sjn = csr_src[jn];
            int ejn = csr_eid[jn];
            unsigned kn = *(const unsigned*)(KVp + (size_t)sjn * 256 + c2);
            unsigned vn = *(const unsigned*)(KVp + (size_t)sjn * 256 + 128 + c2);
            unsigned en = *(const unsigned*)(EEc + (size_t)ejn * 128 + c2);

            float e0 = bf2f((unsigned short)(ec & 0xFFFFu));
            float e1 = bf2f((unsigned short)(ec >> 16));
            float k0 = bf2f((unsigned short)(kc & 0xFFFFu));
            float k1 = bf2f((unsigned short)(kc >> 16));
            float v0 = bf2f((unsigned short)(vc & 0xFFFFu));
            float v1 = bf2f((unsigned short)(vc >> 16));

            float t = q.x * (k0 + e0) + q.y * (k1 + e1);
            t += __shfl_xor(t, 1); t += __shfl_xor(t, 2);
            t += __shfl_xor(t, 4); t += __shfl_xor(t, 8);
            float alpha = t;   // ATT_SCALE pre-folded into Q
            float mn = fmaxf(m, alpha);
            float r = __expf(m - mn);
            float p = __expf(alpha - mn);
            s = s * r + p;
            a0 = a0 * r + p * (v0 + e0);
            a1 = a1 * r + p * (v1 + e1);
            m = mn;
            kc = kn; vc = vn; ec = en;
        }
        float inv = 1.f / (s + 1e-16f);
        float2 h = *(const float2*)(Hskip + (size_t)d * OUTF + c2);
        float2 o;
        o.x = a0 * inv + h.x;
        o.y = a1 * inv + h.y;
        *(float2*)(Out + (size_t)d * OUTF + c2) = o;
    }
}

extern "C" void kernel_launch(void* const* d_in, const int* in_sizes, int n_in,
                              void* d_out, int out_size, void* d_ws, size_t ws_size,
                              hipStream_t stream) {
    const float* x    = (const float*)d_in[0];
    const int*   ei   = (const int*)d_in[1];
    const float* ea   = (const float*)d_in[2];
    const float* emb  = (const float*)d_in[3];
    const float* w1q  = (const float*)d_in[4];  const float* b1q = (const float*)d_in[5];
    const float* w1k  = (const float*)d_in[6];  const float* b1k = (const float*)d_in[7];
    const float* w1v  = (const float*)d_in[8];  const float* b1v = (const float*)d_in[9];
    const float* w1e  = (const float*)d_in[10];
    const float* w1s  = (const float*)d_in[11]; const float* b1s = (const float*)d_in[12];
    const float* w2q  = (const float*)d_in[13]; const float* b2q = (const float*)d_in[14];
    const float* w2k  = (const float*)d_in[15]; const float* b2k = (const float*)d_in[16];
    const float* w2v  = (const float*)d_in[17]; const float* b2v = (const float*)d_in[18];
    const float* w2e  = (const float*)d_in[19];
    const float* w2s  = (const float*)d_in[20]; const float* b2s = (const float*)d_in[21];

    const int* srcI = ei;
    const int* dstI = ei + NE;

    float* Q = (float*)d_ws;                                        // N x 128 f32 (pre-scaled)
    unsigned short* KV = (unsigned short*)(Q + (size_t)NN * OUTF);  // N x 256 bf16 [K|V]
    float* H = (float*)(KV + (size_t)NN * 256);                     // N x 128 f32
    unsigned short* EE1 = (unsigned short*)(H + (size_t)NN * OUTF); // E x 128 bf16 (layer-1 ee)
    unsigned short* EAb = EE1 + (size_t)NE * 128;                   // E x 128 bf16 (becomes EE2 in-place)
    int* csr_src   = (int*)(EAb + (size_t)NE * 128);
    int* csr_eid   = csr_src + NE;
    int* row_start = csr_eid + NE;            // N+1
    int* cursor    = row_start + NN + 1;
    int* cnt       = cursor + NN;
    int* S1        = cnt + NN;
    int* bsum      = S1 + NN;
    int* boff      = bsum + NSCANB;
    unsigned short* WT1  = (unsigned short*)(boff + NSCANB + 1);
    unsigned short* WT2  = WT1 + 512 * KPAD;
    unsigned short* WmT1 = WT2 + 512 * KPAD;
    unsigned short* WmT2 = WmT1 + OUTF * KPAD;
    float* bias1 = (float*)(WmT2 + OUTF * KPAD);
    float* bias2 = bias1 + 512;

    prep_weights<<<128, 256, 0, stream>>>(w1q, w1k, w1v, w1s, w2q, w2k, w2v, w2s,
                                          w1e, w2e, emb,
                                          b1q, b1k, b1v, b1s, b2q, b2k, b2v, b2s,
                                          WT1, WT2, WmT1, WmT2, bias1, bias2);
    hipMemsetAsync(cnt, 0, (size_t)NN * sizeof(int), stream);
    hist_kernel<<<NE / 256, 256, 0, stream>>>(dstI, cnt);
    scan1<<<NSCANB, 256, 0, stream>>>(cnt, S1, bsum);
    scan2<<<1, 512, 0, stream>>>(bsum, boff);
    scan3<<<NSCANB, 256, 0, stream>>>(S1, boff, cnt, row_start, cursor);
    scatter_csr<<<NE / 256, 256, 0, stream>>>(srcI, dstI, cursor, csr_src, csr_eid);
    convert_ea<<<4096, 256, 0, stream>>>(ea, EAb);

    int ngrid = (NN + 127) / 128;
    int egrid = NE / 64;   // 10000

    // ---- node features L1 + both layers' edge GEMM (EAb read; layer 2 in-place) ----
    node_mfma<<<ngrid, 256, 0, stream>>>(x, K1, K1, 0, NN, WT1, bias1, Q, KV, H);
    edge_mfma_one<<<egrid, 256, 0, stream>>>(EAb, WmT1, EE1);
    edge_mfma_one<<<egrid, 256, 0, stream>>>(EAb, WmT2, EAb);   // EE2 overwrites EAb (wave-private rows)
    attn_node<<<2048, 256, 0, stream>>>(Q, KV, EE1, row_start, csr_src, csr_eid, H, H);

    // ---- layer 2 ----
    node_mfma<<<ngrid, 256, 0, stream>>>(H, OUTF, OUTF, 1, NN, WT2, bias2, Q, KV, (float*)d_out);
    attn_node<<<2048, 256, 0, stream>>>(Q, KV, EAb, row_start, csr_src, csr_eid, (float*)d_out, (float*)d_out);
}

// Round 12
// 1138.170 us; speedup vs baseline: 1.1903x; 1.1903x over previous
//
#include <hip/hip_runtime.h>

#define NN 100000
#define NE 640000
#define OUTF 128
#define K1 100
#define KE 118
#define KPAD 128
#define ASTR 136              // padded LDS row stride (ushorts)
#define ATT_SCALE 0.17677669529663687f
#define NSCANB 391            // ceil(NN/256)

typedef __attribute__((ext_vector_type(8))) short short8;
typedef __attribute__((ext_vector_type(4))) float f32x4;

__device__ __forceinline__ unsigned short f2bf(float f) {
    unsigned u = __float_as_uint(f);
    u += 0x7FFFu + ((u >> 16) & 1u);   // RNE
    return (unsigned short)(u >> 16);
}
__device__ __forceinline__ float bf2f(unsigned short h) {
    return __uint_as_float(((unsigned)h) << 16);
}

// ---------- prep: transposed bf16 weights [col][k]; WmT rows 118-121 = one-hot etype tables ----------
__global__ void prep_weights(
    const float* __restrict__ w1q, const float* __restrict__ w1k,
    const float* __restrict__ w1v, const float* __restrict__ w1s,
    const float* __restrict__ w2q, const float* __restrict__ w2k,
    const float* __restrict__ w2v, const float* __restrict__ w2s,
    const float* __restrict__ we1, const float* __restrict__ we2,
    const float* __restrict__ emb,
    const float* __restrict__ b1q, const float* __restrict__ b1k,
    const float* __restrict__ b1v, const float* __restrict__ b1s,
    const float* __restrict__ b2q, const float* __restrict__ b2k,
    const float* __restrict__ b2v, const float* __restrict__ b2s,
    unsigned short* __restrict__ WT1, unsigned short* __restrict__ WT2,
    unsigned short* __restrict__ WmT1, unsigned short* __restrict__ WmT2,
    float* __restrict__ bias1, float* __restrict__ bias2)
{
    int idx = blockIdx.x * blockDim.x + threadIdx.x;
    int stride = gridDim.x * blockDim.x;
    for (int i = idx; i < 512 * KPAD; i += stride) {
        int col = i >> 7, k = i & 127;
        int which = col >> 7, c = col & 127;
        const float* s1 = (which == 0) ? w1q : (which == 1) ? w1k : (which == 2) ? w1v : w1s;
        const float* s2 = (which == 0) ? w2q : (which == 1) ? w2k : (which == 2) ? w2v : w2s;
        float v1 = (k < K1) ? s1[k * OUTF + c] : 0.f;
        float v2 = s2[k * OUTF + c];
        WT1[i] = f2bf(v1); WT2[i] = f2bf(v2);
    }
    for (int i = idx; i < OUTF * KPAD; i += stride) {
        int col = i >> 7, k = i & 127;
        float v1 = 0.f, v2 = 0.f;
        if (k < 3)                 { v1 = we1[k * OUTF + col];       v2 = we2[k * OUTF + col]; }
        else if (k >= 4 && k < KE) { v1 = we1[(k - 1) * OUTF + col]; v2 = we2[(k - 1) * OUTF + col]; }
        else if (k >= KE && k < KE + 4) {
            int t = k - KE;
            #pragma unroll
            for (int r = 0; r < 8; r++) {
                float ev = emb[t * 8 + r];
                v1 += ev * we1[(117 + r) * OUTF + col];
                v2 += ev * we2[(117 + r) * OUTF + col];
            }
        }
        WmT1[i] = f2bf(v1); WmT2[i] = f2bf(v2);
    }
    for (int i = idx; i < 512; i += stride) {
        int which = i >> 7, c = i & 127;
        const float* sb1 = (which == 0) ? b1q : (which == 1) ? b1k : (which == 2) ? b1v : b1s;
        const float* sb2 = (which == 0) ? b2q : (which == 1) ? b2k : (which == 2) ? b2v : b2s;
        bias1[i] = sb1[c]; bias2[i] = sb2[c];
    }
}

// ---------- once: EA fp32 -> EAb bf16 [E][128], one-hot etype baked; pure streaming ----------
__global__ __launch_bounds__(256) void convert_ea(const float* __restrict__ EA,
                                                  unsigned short* __restrict__ EAb)
{
    int lane = threadIdx.x & 63;
    int gw = (int)((blockIdx.x * (size_t)blockDim.x + threadIdx.x) >> 6);
    int nW = (gridDim.x * blockDim.x) >> 6;
    int k = lane * 2;
    for (int e = gw; e < NE; e += nW) {
        const float* row = EA + (size_t)e * KE;
        float2 v = make_float2(0.f, 0.f);
        if (k < KE) v = *(const float2*)(row + k);
        int et = (int)row[3];                 // broadcast load, L1-served
        if (lane == 1) v.y = 0.f;             // col 3 = etype -> zero
        int oh = KE + et;                     // one-hot col 118..121
        if (k == oh)     v.x = 1.f;
        if (k + 1 == oh) v.y = 1.f;
        unsigned pv = (unsigned)f2bf(v.x) | ((unsigned)f2bf(v.y) << 16);
        *(unsigned*)(EAb + (size_t)e * 128 + k) = pv;
    }
}

// ---------- CSR build ----------
__global__ void hist_kernel(const int* __restrict__ dstI, int* __restrict__ cnt) {
    int e = blockIdx.x * 256 + threadIdx.x;
    if (e < NE) atomicAdd(&cnt[dstI[e]], 1);
}
__global__ void scan1(const int* __restrict__ cnt, int* __restrict__ S1, int* __restrict__ bsum) {
    __shared__ int sd[256];
    int t = blockIdx.x * 256 + threadIdx.x;
    sd[threadIdx.x] = (t < NN) ? cnt[t] : 0;
    __syncthreads();
    for (int off = 1; off < 256; off <<= 1) {
        int x = (threadIdx.x >= off) ? sd[threadIdx.x - off] : 0;
        __syncthreads();
        sd[threadIdx.x] += x;
        __syncthreads();
    }
    if (t < NN) S1[t] = sd[threadIdx.x];
    if (threadIdx.x == 255) bsum[blockIdx.x] = sd[255];
}
__global__ void scan2(const int* __restrict__ bsum, int* __restrict__ boff) {
    __shared__ int sd[512];
    int t = threadIdx.x;
    sd[t] = (t < NSCANB) ? bsum[t] : 0;
    __syncthreads();
    for (int off = 1; off < 512; off <<= 1) {
        int x = (t >= off) ? sd[t - off] : 0;
        __syncthreads();
        sd[t] += x;
        __syncthreads();
    }
    if (t < NSCANB) boff[t] = (t == 0) ? 0 : sd[t - 1];
}
__global__ void scan3(const int* __restrict__ S1, const int* __restrict__ boff,
                      const int* __restrict__ cnt,
                      int* __restrict__ row_start, int* __restrict__ cursor) {
    int t = blockIdx.x * 256 + threadIdx.x;
    if (t < NN) {
        int incl = S1[t] + boff[t >> 8];
        row_start[t + 1] = incl;
        cursor[t] = incl - cnt[t];
        if (t == 0) row_start[0] = 0;
    }
}
__global__ void scatter_csr(const int* __restrict__ srcI, const int* __restrict__ dstI,
                            int* __restrict__ cursor,
                            int* __restrict__ csr_src, int* __restrict__ csr_eid) {
    int e = blockIdx.x * 256 + threadIdx.x;
    if (e < NE) {
        int j = atomicAdd(&cursor[dstI[e]], 1);
        csr_src[j] = srcI[e];
        csr_eid[j] = e;
    }
}

// ---------- node GEMM, one 128-col block per block: coalesced LDS-staged epilogue ----------
// grid = ngrid*4; blockIdx = rowtile*4 + nb. nb: 0=Q(f32, pre-scaled) 1=K(bf16) 2=V(bf16) 3=H(f32)
__global__ __launch_bounds__(256) void node_mfma(
    const float* __restrict__ X, int ldx, int Kdim, int relu, int n,
    const unsigned short* __restrict__ WT, const float* __restrict__ bias,
    float* __restrict__ Qp, unsigned short* __restrict__ KVp, float* __restrict__ Hp)
{
    __shared__ unsigned short Alds[128][ASTR];     // A tile; reused as output staging after MFMA
    int tid = threadIdx.x;
    int rowbase = (blockIdx.x >> 2) * 128;
    int nb = blockIdx.x & 3;

    for (int idx = tid; idx < 128 * 68; idx += 256) {
        int r = idx / 68, kv = idx % 68;
        int k = kv * 2;
        float2 v = make_float2(0.f, 0.f);
        int gr = rowbase + r;
        if (gr < n && k < Kdim) v = *(const float2*)(X + (size_t)gr * ldx + k);
        if (relu) { v.x = fmaxf(v.x, 0.f); v.y = fmaxf(v.y, 0.f); }
        unsigned pv = (unsigned)f2bf(v.x) | ((unsigned)f2bf(v.y) << 16);
        *(unsigned*)&Alds[r][k] = pv;
    }
    __syncthreads();

    int lane = tid & 63, wid = tid >> 6;
    int wm = wid >> 1, wn = wid & 1;
    int l15 = lane & 15, l4 = lane >> 4;

    f32x4 acc[4][4];
    #pragma unroll
    for (int mf = 0; mf < 4; mf++)
        #pragma unroll
        for (int nf = 0; nf < 4; nf++)
            acc[mf][nf] = (f32x4){0.f, 0.f, 0.f, 0.f};

    const unsigned short* wbase = WT + (size_t)(nb * 128 + wn * 64 + l15) * KPAD + l4 * 8;
    #pragma unroll
    for (int ks = 0; ks < 4; ks++) {
        short8 af[4], bfr[4];
        #pragma unroll
        for (int mf = 0; mf < 4; mf++)
            af[mf] = *(const short8*)&Alds[wm * 64 + mf * 16 + l15][ks * 32 + l4 * 8];
        #pragma unroll
        for (int nf = 0; nf < 4; nf++)
            bfr[nf] = *(const short8*)(wbase + (size_t)nf * 16 * KPAD + ks * 32);
        #pragma unroll
        for (int mf = 0; mf < 4; mf++)
            #pragma unroll
            for (int nf = 0; nf < 4; nf++)
                acc[mf][nf] = __builtin_amdgcn_mfma_f32_16x16x32_bf16(af[mf], bfr[nf], acc[mf][nf], 0, 0, 0);
    }
    __syncthreads();   // A tile dead; reuse LDS for output staging

    if (nb == 1 || nb == 2) {
        // --- bf16 K/V: one 128x128 ushort tile, uint4 stores (full 256B rows) ---
        #pragma unroll
        for (int nf = 0; nf < 4; nf++) {
            int col = wn * 64 + nf * 16 + l15;
            float bv = bias[nb * 128 + col];
            #pragma unroll
            for (int mf = 0; mf < 4; mf++)
                #pragma unroll
                for (int rr = 0; rr < 4; rr++)
                    Alds[wm * 64 + mf * 16 + l4 * 4 + rr][col] = f2bf(acc[mf][nf][rr] + bv);
        }
        __syncthreads();
        int off = (nb == 1) ? 0 : 128;
        #pragma unroll
        for (int it = 0; it < 8; it++) {
            int idx = it * 256 + tid;
            int row = idx >> 4, c8 = (idx & 15) * 8;
            if (rowbase + row < n) {
                uint4 v = *(const uint4*)&Alds[row][c8];
                *(uint4*)(KVp + (size_t)(rowbase + row) * 256 + off + c8) = v;
            }
        }
    } else {
        // --- f32 Q/H: two 64-col half tiles ([128][68] f32 == Alds footprint), float4 stores ---
        float* Yp = (nb == 0) ? Qp : Hp;
        float scale = (nb == 0) ? ATT_SCALE : 1.f;
        float (*Sf)[68] = (float (*)[68])Alds;
        #pragma unroll
        for (int h = 0; h < 2; h++) {
            if (wn == h) {
                #pragma unroll
                for (int nf = 0; nf < 4; nf++) {
                    int col = wn * 64 + nf * 16 + l15;
                    float bv = bias[nb * 128 + col];
                    #pragma unroll
                    for (int mf = 0; mf < 4; mf++)
                        #pragma unroll
                        for (int rr = 0; rr < 4; rr++)
                            Sf[wm * 64 + mf * 16 + l4 * 4 + rr][nf * 16 + l15] =
                                (acc[mf][nf][rr] + bv) * scale;
                }
            }
            __syncthreads();
            #pragma unroll
            for (int it = 0; it < 8; it++) {
                int idx = it * 256 + tid;
                int row = idx >> 4, c4 = (idx & 15) * 4;
                if (rowbase + row < n) {
                    float4 v = *(const float4*)&Sf[row][c4];
                    *(float4*)(Yp + (size_t)(rowbase + row) * OUTF + h * 64 + c4) = v;
                }
            }
            if (h == 0) __syncthreads();
        }
    }
}

// ---------- per-layer edge GEMM: barrier-free, A-frags direct from global, linear EE store ----------
__global__ __launch_bounds__(256) void edge_mfma_one(
    const unsigned short* __restrict__ EAb,
    const unsigned short* __restrict__ WmT,
    unsigned short* EEc)
{
    __shared__ unsigned short Tlds[64][ASTR];
    int tid = threadIdx.x;
    int lane = tid & 63, w = tid >> 6;
    int e0 = blockIdx.x * 64;
    int l15 = lane & 15, l4 = lane >> 4;
    int rbase = w * 16;

    short8 af[4];
    #pragma unroll
    for (int ks = 0; ks < 4; ks++)
        af[ks] = *(const short8*)(EAb + (size_t)(e0 + rbase + l15) * 128 + ks * 32 + l4 * 8);

    f32x4 acc[8];
    #pragma unroll
    for (int nf = 0; nf < 8; nf++) acc[nf] = (f32x4){0.f, 0.f, 0.f, 0.f};

    #pragma unroll
    for (int ks = 0; ks < 4; ks++) {
        short8 bfr[8];
        #pragma unroll
        for (int nf = 0; nf < 8; nf++)
            bfr[nf] = *(const short8*)(WmT + (size_t)(nf * 16 + l15) * KPAD + ks * 32 + l4 * 8);
        #pragma unroll
        for (int nf = 0; nf < 8; nf++)
            acc[nf] = __builtin_amdgcn_mfma_f32_16x16x32_bf16(af[ks], bfr[nf], acc[nf], 0, 0, 0);
    }

    #pragma unroll
    for (int nf = 0; nf < 8; nf++)
        #pragma unroll
        for (int rr = 0; rr < 4; rr++)
            Tlds[rbase + l4 * 4 + rr][nf * 16 + l15] = f2bf(acc[nf][rr]);
    #pragma unroll
    for (int it = 0; it < 4; it++) {
        int t2 = it * 64 + lane;
        int rid = t2 >> 4, c8 = (t2 & 15) * 8;
        uint4 v = *(const uint4*)&Tlds[rbase + rid][c8];
        *(uint4*)(EEc + ((size_t)(e0 + rbase + rid)) * 128 + c8) = v;
    }
}

// ---------- fused attn: one wave per dst, online softmax, 1-deep prefetch, EE gathered by eid ----------
__global__ __launch_bounds__(256) void attn_node(
    const float* __restrict__ Qp, const unsigned short* __restrict__ KVp,
    const unsigned short* __restrict__ EEc,
    const int* __restrict__ row_start, const int* __restrict__ csr_src,
    const int* __restrict__ csr_eid,
    const float* __restrict__ Hskip, float* __restrict__ Out)
{
    int lane = threadIdx.x & 63;
    int gw = (int)((blockIdx.x * (size_t)blockDim.x + threadIdx.x) >> 6);
    int nW = (gridDim.x * blockDim.x) >> 6;
    int c2 = lane * 2;

    for (int d = gw; d < NN; d += nW) {
        int rs = row_start[d], re = row_start[d + 1];
        float2 q = *(const float2*)(Qp + (size_t)d * OUTF + c2);
        float m = -3.4e38f, s = 0.f, a0 = 0.f, a1 = 0.f;

        int j0 = (rs < re) ? rs : 0;
        int sj = csr_src[j0];
        int ej = csr_eid[j0];
        unsigned kc = *(const unsigned*)(KVp + (size_t)sj * 256 + c2);
        unsigned vc = *(const unsigned*)(KVp + (size_t)sj * 256 + 128 + c2);
        unsigned ec = *(const unsigned*)(EEc + (size_t)ej * 128 + c2);

        for (int j = rs; j < re; j++) {
            int jn = (j + 1 < re) ? j + 1 : j;
            int sjn = csr_src[jn];
            int ejn = csr_eid[jn];
            unsigned kn = *(const unsigned*)(KVp + (size_t)sjn * 256 + c2);
            unsigned vn = *(const unsigned*)(KVp + (size_t)sjn * 256 + 128 + c2);
            unsigned en = *(const unsigned*)(EEc + (size_t)ejn * 128 + c2);

            float e0 = bf2f((unsigned short)(ec & 0xFFFFu));
            float e1 = bf2f((unsigned short)(ec >> 16));
            float k0 = bf2f((unsigned short)(kc & 0xFFFFu));
            float k1 = bf2f((unsigned short)(kc >> 16));
            float v0 = bf2f((unsigned short)(vc & 0xFFFFu));
            float v1 = bf2f((unsigned short)(vc >> 16));

            float t = q.x * (k0 + e0) + q.y * (k1 + e1);
            t += __shfl_xor(t, 1); t += __shfl_xor(t, 2);
            t += __shfl_xor(t, 4); t += __shfl_xor(t, 8);
            float alpha = t;   // ATT_SCALE pre-folded into Q
            float mn = fmaxf(m, alpha);
            float r = __expf(m - mn);
            float p = __expf(alpha - mn);
            s = s * r + p;
            a0 = a0 * r + p * (v0 + e0);
            a1 = a1 * r + p * (v1 + e1);
            m = mn;
            kc = kn; vc = vn; ec = en;
        }
        float inv = 1.f / (s + 1e-16f);
        float2 h = *(const float2*)(Hskip + (size_t)d * OUTF + c2);
        float2 o;
        o.x = a0 * inv + h.x;
        o.y = a1 * inv + h.y;
        *(float2*)(Out + (size_t)d * OUTF + c2) = o;
    }
}

extern "C" void kernel_launch(void* const* d_in, const int* in_sizes, int n_in,
                              void* d_out, int out_size, void* d_ws, size_t ws_size,
                              hipStream_t stream) {
    const float* x    = (const float*)d_in[0];
    const int*   ei   = (const int*)d_in[1];
    const float* ea   = (const float*)d_in[2];
    const float* emb  = (const float*)d_in[3];
    const float* w1q  = (const float*)d_in[4];  const float* b1q = (const float*)d_in[5];
    const float* w1k  = (const float*)d_in[6];  const float* b1k = (const float*)d_in[7];
    const float* w1v  = (const float*)d_in[8];  const float* b1v = (const float*)d_in[9];
    const float* w1e  = (const float*)d_in[10];
    const float* w1s  = (const float*)d_in[11]; const float* b1s = (const float*)d_in[12];
    const float* w2q  = (const float*)d_in[13]; const float* b2q = (const float*)d_in[14];
    const float* w2k  = (const float*)d_in[15]; const float* b2k = (const float*)d_in[16];
    const float* w2v  = (const float*)d_in[17]; const float* b2v = (const float*)d_in[18];
    const float* w2e  = (const float*)d_in[19];
    const float* w2s  = (const float*)d_in[20]; const float* b2s = (const float*)d_in[21];

    const int* srcI = ei;
    const int* dstI = ei + NE;

    float* Q = (float*)d_ws;                                        // N x 128 f32 (pre-scaled)
    unsigned short* KV = (unsigned short*)(Q + (size_t)NN * OUTF);  // N x 256 bf16 [K|V]
    float* H = (float*)(KV + (size_t)NN * 256);                     // N x 128 f32
    unsigned short* EE1 = (unsigned short*)(H + (size_t)NN * OUTF); // E x 128 bf16 (layer-1 ee)
    unsigned short* EAb = EE1 + (size_t)NE * 128;                   // E x 128 bf16 (becomes EE2 in-place)
    int* csr_src   = (int*)(EAb + (size_t)NE * 128);
    int* csr_eid   = csr_src + NE;
    int* row_start = csr_eid + NE;            // N+1
    int* cursor    = row_start + NN + 1;
    int* cnt       = cursor + NN;
    int* S1        = cnt + NN;
    int* bsum      = S1 + NN;
    int* boff      = bsum + NSCANB;
    unsigned short* WT1  = (unsigned short*)(boff + NSCANB + 1);
    unsigned short* WT2  = WT1 + 512 * KPAD;
    unsigned short* WmT1 = WT2 + 512 * KPAD;
    unsigned short* WmT2 = WmT1 + OUTF * KPAD;
    float* bias1 = (float*)(WmT2 + OUTF * KPAD);
    float* bias2 = bias1 + 512;

    prep_weights<<<128, 256, 0, stream>>>(w1q, w1k, w1v, w1s, w2q, w2k, w2v, w2s,
                                          w1e, w2e, emb,
                                          b1q, b1k, b1v, b1s, b2q, b2k, b2v, b2s,
                                          WT1, WT2, WmT1, WmT2, bias1, bias2);
    hipMemsetAsync(cnt, 0, (size_t)NN * sizeof(int), stream);
    hist_kernel<<<NE / 256, 256, 0, stream>>>(dstI, cnt);
    scan1<<<NSCANB, 256, 0, stream>>>(cnt, S1, bsum);
    scan2<<<1, 512, 0, stream>>>(bsum, boff);
    scan3<<<NSCANB, 256, 0, stream>>>(S1, boff, cnt, row_start, cursor);
    scatter_csr<<<NE / 256, 256, 0, stream>>>(srcI, dstI, cursor, csr_src, csr_eid);
    convert_ea<<<4096, 256, 0, stream>>>(ea, EAb);

    int ngrid = ((NN + 127) / 128) * 4;   // 782 row-tiles x 4 col-blocks = 3128
    int egrid = NE / 64;                  // 10000

    // ---- node features L1 + both layers' edge GEMM (EAb read; layer 2 in-place) ----
    node_mfma<<<ngrid, 256, 0, stream>>>(x, K1, K1, 0, NN, WT1, bias1, Q, KV, H);
    edge_mfma_one<<<egrid, 256, 0, stream>>>(EAb, WmT1, EE1);
    edge_mfma_one<<<egrid, 256, 0, stream>>>(EAb, WmT2, EAb);   // EE2 overwrites EAb (wave-private rows)
    attn_node<<<2048, 256, 0, stream>>>(Q, KV, EE1, row_start, csr_src, csr_eid, H, H);

    // ---- layer 2 ----
    node_mfma<<<ngrid, 256, 0, stream>>>(H, OUTF, OUTF, 1, NN, WT2, bias2, Q, KV, (float*)d_out);
    attn_node<<<2048, 256, 0, stream>>>(Q, KV, EAb, row_start, csr_src, csr_eid, (float*)d_out, (float*)d_out);
}

// Round 13
// 1122.873 us; speedup vs baseline: 1.2065x; 1.0136x over previous
//
#include <hip/hip_runtime.h>

#define NN 100000
#define NE 640000
#define OUTF 128
#define K1 100
#define KE 118
#define KPAD 128
#define ASTR 136              // padded LDS row stride (ushorts)
#define ATT_SCALE 0.17677669529663687f
#define NSCANB 391            // ceil(NN/256)

typedef __attribute__((ext_vector_type(8))) short short8;
typedef __attribute__((ext_vector_type(4))) float f32x4;

__device__ __forceinline__ unsigned short f2bf(float f) {
    unsigned u = __float_as_uint(f);
    u += 0x7FFFu + ((u >> 16) & 1u);   // RNE
    return (unsigned short)(u >> 16);
}
__device__ __forceinline__ float bf2f(unsigned short h) {
    return __uint_as_float(((unsigned)h) << 16);
}

// ---------- prep: transposed bf16 weights [col][k]; WmT rows 118-121 = one-hot etype tables ----------
__global__ void prep_weights(
    const float* __restrict__ w1q, const float* __restrict__ w1k,
    const float* __restrict__ w1v, const float* __restrict__ w1s,
    const float* __restrict__ w2q, const float* __restrict__ w2k,
    const float* __restrict__ w2v, const float* __restrict__ w2s,
    const float* __restrict__ we1, const float* __restrict__ we2,
    const float* __restrict__ emb,
    const float* __restrict__ b1q, const float* __restrict__ b1k,
    const float* __restrict__ b1v, const float* __restrict__ b1s,
    const float* __restrict__ b2q, const float* __restrict__ b2k,
    const float* __restrict__ b2v, const float* __restrict__ b2s,
    unsigned short* __restrict__ WT1, unsigned short* __restrict__ WT2,
    unsigned short* __restrict__ WmT1, unsigned short* __restrict__ WmT2,
    float* __restrict__ bias1, float* __restrict__ bias2)
{
    int idx = blockIdx.x * blockDim.x + threadIdx.x;
    int stride = gridDim.x * blockDim.x;
    for (int i = idx; i < 512 * KPAD; i += stride) {
        int col = i >> 7, k = i & 127;
        int which = col >> 7, c = col & 127;
        const float* s1 = (which == 0) ? w1q : (which == 1) ? w1k : (which == 2) ? w1v : w1s;
        const float* s2 = (which == 0) ? w2q : (which == 1) ? w2k : (which == 2) ? w2v : w2s;
        float v1 = (k < K1) ? s1[k * OUTF + c] : 0.f;
        float v2 = s2[k * OUTF + c];
        WT1[i] = f2bf(v1); WT2[i] = f2bf(v2);
    }
    for (int i = idx; i < OUTF * KPAD; i += stride) {
        int col = i >> 7, k = i & 127;
        float v1 = 0.f, v2 = 0.f;
        if (k < 3)                 { v1 = we1[k * OUTF + col];       v2 = we2[k * OUTF + col]; }
        else if (k >= 4 && k < KE) { v1 = we1[(k - 1) * OUTF + col]; v2 = we2[(k - 1) * OUTF + col]; }
        else if (k >= KE && k < KE + 4) {
            int t = k - KE;
            #pragma unroll
            for (int r = 0; r < 8; r++) {
                float ev = emb[t * 8 + r];
                v1 += ev * we1[(117 + r) * OUTF + col];
                v2 += ev * we2[(117 + r) * OUTF + col];
            }
        }
        WmT1[i] = f2bf(v1); WmT2[i] = f2bf(v2);
    }
    for (int i = idx; i < 512; i += stride) {
        int which = i >> 7, c = i & 127;
        const float* sb1 = (which == 0) ? b1q : (which == 1) ? b1k : (which == 2) ? b1v : b1s;
        const float* sb2 = (which == 0) ? b2q : (which == 1) ? b2k : (which == 2) ? b2v : b2s;
        bias1[i] = sb1[c]; bias2[i] = sb2[c];
    }
}

// ---------- CSR build ----------
__global__ void hist_kernel(const int* __restrict__ dstI, int* __restrict__ cnt) {
    int e = blockIdx.x * 256 + threadIdx.x;
    if (e < NE) atomicAdd(&cnt[dstI[e]], 1);
}
__global__ void scan1(const int* __restrict__ cnt, int* __restrict__ S1, int* __restrict__ bsum) {
    __shared__ int sd[256];
    int t = blockIdx.x * 256 + threadIdx.x;
    sd[threadIdx.x] = (t < NN) ? cnt[t] : 0;
    __syncthreads();
    for (int off = 1; off < 256; off <<= 1) {
        int x = (threadIdx.x >= off) ? sd[threadIdx.x - off] : 0;
        __syncthreads();
        sd[threadIdx.x] += x;
        __syncthreads();
    }
    if (t < NN) S1[t] = sd[threadIdx.x];
    if (threadIdx.x == 255) bsum[blockIdx.x] = sd[255];
}
__global__ void scan2(const int* __restrict__ bsum, int* __restrict__ boff) {
    __shared__ int sd[512];
    int t = threadIdx.x;
    sd[t] = (t < NSCANB) ? bsum[t] : 0;
    __syncthreads();
    for (int off = 1; off < 512; off <<= 1) {
        int x = (t >= off) ? sd[t - off] : 0;
        __syncthreads();
        sd[t] += x;
        __syncthreads();
    }
    if (t < NSCANB) boff[t] = (t == 0) ? 0 : sd[t - 1];
}
__global__ void scan3(const int* __restrict__ S1, const int* __restrict__ boff,
                      const int* __restrict__ cnt,
                      int* __restrict__ row_start, int* __restrict__ cursor) {
    int t = blockIdx.x * 256 + threadIdx.x;
    if (t < NN) {
        int incl = S1[t] + boff[t >> 8];
        row_start[t + 1] = incl;
        cursor[t] = incl - cnt[t];
        if (t == 0) row_start[0] = 0;
    }
}
__global__ void scatter_csr(const int* __restrict__ srcI, const int* __restrict__ dstI,
                            int* __restrict__ cursor,
                            int* __restrict__ csr_src, int* __restrict__ csr_eid) {
    int e = blockIdx.x * 256 + threadIdx.x;
    if (e < NE) {
        int j = atomicAdd(&cursor[dstI[e]], 1);
        csr_src[j] = srcI[e];
        csr_eid[j] = e;
    }
}

// ---------- node GEMM, one 128-col block per block: coalesced LDS-staged epilogue ----------
// grid = ngrid*4; blockIdx = rowtile*4 + nb. nb: 0=Q(f32, pre-scaled) 1=K(bf16) 2=V(bf16) 3=H(f32)
__global__ __launch_bounds__(256) void node_mfma(
    const float* __restrict__ X, int ldx, int Kdim, int relu, int n,
    const unsigned short* __restrict__ WT, const float* __restrict__ bias,
    float* __restrict__ Qp, unsigned short* __restrict__ KVp, float* __restrict__ Hp)
{
    __shared__ unsigned short Alds[128][ASTR];     // A tile; reused as output staging after MFMA
    int tid = threadIdx.x;
    int rowbase = (blockIdx.x >> 2) * 128;
    int nb = blockIdx.x & 3;

    for (int idx = tid; idx < 128 * 68; idx += 256) {
        int r = idx / 68, kv = idx % 68;
        int k = kv * 2;
        float2 v = make_float2(0.f, 0.f);
        int gr = rowbase + r;
        if (gr < n && k < Kdim) v = *(const float2*)(X + (size_t)gr * ldx + k);
        if (relu) { v.x = fmaxf(v.x, 0.f); v.y = fmaxf(v.y, 0.f); }
        unsigned pv = (unsigned)f2bf(v.x) | ((unsigned)f2bf(v.y) << 16);
        *(unsigned*)&Alds[r][k] = pv;
    }
    __syncthreads();

    int lane = tid & 63, wid = tid >> 6;
    int wm = wid >> 1, wn = wid & 1;
    int l15 = lane & 15, l4 = lane >> 4;

    f32x4 acc[4][4];
    #pragma unroll
    for (int mf = 0; mf < 4; mf++)
        #pragma unroll
        for (int nf = 0; nf < 4; nf++)
            acc[mf][nf] = (f32x4){0.f, 0.f, 0.f, 0.f};

    const unsigned short* wbase = WT + (size_t)(nb * 128 + wn * 64 + l15) * KPAD + l4 * 8;
    #pragma unroll
    for (int ks = 0; ks < 4; ks++) {
        short8 af[4], bfr[4];
        #pragma unroll
        for (int mf = 0; mf < 4; mf++)
            af[mf] = *(const short8*)&Alds[wm * 64 + mf * 16 + l15][ks * 32 + l4 * 8];
        #pragma unroll
        for (int nf = 0; nf < 4; nf++)
            bfr[nf] = *(const short8*)(wbase + (size_t)nf * 16 * KPAD + ks * 32);
        #pragma unroll
        for (int mf = 0; mf < 4; mf++)
            #pragma unroll
            for (int nf = 0; nf < 4; nf++)
                acc[mf][nf] = __builtin_amdgcn_mfma_f32_16x16x32_bf16(af[mf], bfr[nf], acc[mf][nf], 0, 0, 0);
    }
    __syncthreads();   // A tile dead; reuse LDS for output staging

    if (nb == 1 || nb == 2) {
        // --- bf16 K/V: one 128x128 ushort tile, uint4 stores (full 256B rows) ---
        #pragma unroll
        for (int nf = 0; nf < 4; nf++) {
            int col = wn * 64 + nf * 16 + l15;
            float bv = bias[nb * 128 + col];
            #pragma unroll
            for (int mf = 0; mf < 4; mf++)
                #pragma unroll
                for (int rr = 0; rr < 4; rr++)
                    Alds[wm * 64 + mf * 16 + l4 * 4 + rr][col] = f2bf(acc[mf][nf][rr] + bv);
        }
        __syncthreads();
        int off = (nb == 1) ? 0 : 128;
        #pragma unroll
        for (int it = 0; it < 8; it++) {
            int idx = it * 256 + tid;
            int row = idx >> 4, c8 = (idx & 15) * 8;
            if (rowbase + row < n) {
                uint4 v = *(const uint4*)&Alds[row][c8];
                *(uint4*)(KVp + (size_t)(rowbase + row) * 256 + off + c8) = v;
            }
        }
    } else {
        // --- f32 Q/H: two 64-col half tiles ([128][68] f32 == Alds footprint), float4 stores ---
        float* Yp = (nb == 0) ? Qp : Hp;
        float scale = (nb == 0) ? ATT_SCALE : 1.f;
        float (*Sf)[68] = (float (*)[68])Alds;
        #pragma unroll
        for (int h = 0; h < 2; h++) {
            if (wn == h) {
                #pragma unroll
                for (int nf = 0; nf < 4; nf++) {
                    int col = wn * 64 + nf * 16 + l15;
                    float bv = bias[nb * 128 + col];
                    #pragma unroll
                    for (int mf = 0; mf < 4; mf++)
                        #pragma unroll
                        for (int rr = 0; rr < 4; rr++)
                            Sf[wm * 64 + mf * 16 + l4 * 4 + rr][nf * 16 + l15] =
                                (acc[mf][nf][rr] + bv) * scale;
                }
            }
            __syncthreads();
            #pragma unroll
            for (int it = 0; it < 8; it++) {
                int idx = it * 256 + tid;
                int row = idx >> 4, c4 = (idx & 15) * 4;
                if (rowbase + row < n) {
                    float4 v = *(const float4*)&Sf[row][c4];
                    *(float4*)(Yp + (size_t)(rowbase + row) * OUTF + h * 64 + c4) = v;
                }
            }
            if (h == 0) __syncthreads();
        }
    }
}

// ---------- fused dual-layer edge GEMM: EA fp32 -> LDS bf16 (1 barrier) -> regs -> MFMA x2 -> EE1/EE2 ----------
// 64-row tile, 256 threads / 4 waves / 16 rows per wave; one-hot etype patched in-register.
__global__ __launch_bounds__(256) void edge_mfma_dual(
    const float* __restrict__ EA,
    const unsigned short* __restrict__ WmT1, const unsigned short* __restrict__ WmT2,
    unsigned short* __restrict__ EE1, unsigned short* __restrict__ EE2)
{
    __shared__ unsigned short Alds[64][ASTR];   // A tile; per-wave rows reused as transpose buffer
    __shared__ int et_lds[64];
    int tid = threadIdx.x;
    int e0 = blockIdx.x * 64;
    int lane = tid & 63, w = tid >> 6;
    int l15 = lane & 15, l4 = lane >> 4;
    int rbase = w * 16;

    // stage-in: coalesced (64 lanes cover one row's 472 B), 16 iters
    #pragma unroll 4
    for (int it = 0; it < 16; it++) {
        int idx = it * 256 + tid;
        int r = idx >> 6, slot = idx & 63;
        int k = slot * 2;
        float2 v = make_float2(0.f, 0.f);
        if (k < KE) v = *(const float2*)(EA + (size_t)(e0 + r) * KE + k);
        if (slot == 1) { et_lds[r] = (int)v.y; v.y = 0.f; }   // col 3 = etype
        unsigned pv = (unsigned)f2bf(v.x) | ((unsigned)f2bf(v.y) << 16);
        *(unsigned*)&Alds[r][k] = pv;
    }
    __syncthreads();   // the ONLY barrier

    // A fragments to registers (wave-private afterwards); one-hot patched in-register
    short8 af[4];
    #pragma unroll
    for (int ks = 0; ks < 4; ks++)
        af[ks] = *(const short8*)&Alds[rbase + l15][ks * 32 + l4 * 8];
    int oh = KE + et_lds[rbase + l15];   // one-hot col 118..121, lives in af[3]
    #pragma unroll
    for (int j = 0; j < 8; j++) {
        int col = 96 + l4 * 8 + j;
        if (col == oh) af[3][j] = 0x3F80;  // compile-time index, runtime cndmask
    }

    auto do_layer = [&](const unsigned short* __restrict__ WmT, unsigned short* __restrict__ EEc) {
        f32x4 acc[8];
        #pragma unroll
        for (int nf = 0; nf < 8; nf++) acc[nf] = (f32x4){0.f, 0.f, 0.f, 0.f};

        #pragma unroll
        for (int ks = 0; ks < 4; ks++) {
            short8 bfr[8];
            #pragma unroll
            for (int nf = 0; nf < 8; nf++)
                bfr[nf] = *(const short8*)(WmT + (size_t)(nf * 16 + l15) * KPAD + ks * 32 + l4 * 8);
            #pragma unroll
            for (int nf = 0; nf < 8; nf++)
                acc[nf] = __builtin_amdgcn_mfma_f32_16x16x32_bf16(af[ks], bfr[nf], acc[nf], 0, 0, 0);
        }
        // wave-private transpose through own LDS rows (af already in regs), coalesced linear store
        #pragma unroll
        for (int nf = 0; nf < 8; nf++)
            #pragma unroll
            for (int rr = 0; rr < 4; rr++)
                Alds[rbase + l4 * 4 + rr][nf * 16 + l15] = f2bf(acc[nf][rr]);
        #pragma unroll
        for (int it = 0; it < 4; it++) {
            int t2 = it * 64 + lane;
            int rid = t2 >> 4, c8 = (t2 & 15) * 8;   // rid spans [0,16) over it=0..3
            uint4 v = *(const uint4*)&Alds[rbase + rid][c8];
            *(uint4*)(EEc + ((size_t)(e0 + rbase + rid)) * 128 + c8) = v;
        }
    };
    do_layer(WmT1, EE1);
    do_layer(WmT2, EE2);
}

// ---------- fused attn: one wave per dst, online softmax, 1-deep prefetch, EE gathered by eid ----------
__global__ __launch_bounds__(256) void attn_node(
    const float* __restrict__ Qp, const unsigned short* __restrict__ KVp,
    const unsigned short* __restrict__ EEc,
    const int* __restrict__ row_start, const int* __restrict__ csr_src,
    const int* __restrict__ csr_eid,
    const float* __restrict__ Hskip, float* __restrict__ Out)
{
    int lane = threadIdx.x & 63;
    int gw = (int)((blockIdx.x * (size_t)blockDim.x + threadIdx.x) >> 6);
    int nW = (gridDim.x * blockDim.x) >> 6;
    int c2 = lane * 2;

    for (int d = gw; d < NN; d += nW) {
        int rs = row_start[d], re = row_start[d + 1];
        float2 q = *(const float2*)(Qp + (size_t)d * OUTF + c2);
        float m = -3.4e38f, s = 0.f, a0 = 0.f, a1 = 0.f;

        int j0 = (rs < re) ? rs : 0;
        int sj = csr_src[j0];
        int ej = csr_eid[j0];
        unsigned kc = *(const unsigned*)(KVp + (size_t)sj * 256 + c2);
        unsigned vc = *(const unsigned*)(KVp + (size_t)sj * 256 + 128 + c2);
        unsigned ec = *(const unsigned*)(EEc + (size_t)ej * 128 + c2);

        for (int j = rs; j < re; j++) {
            int jn = (j + 1 < re) ? j + 1 : j;
            int sjn = csr_src[jn];
            int ejn = csr_eid[jn];
            unsigned kn = *(const unsigned*)(KVp + (size_t)sjn * 256 + c2);
            unsigned vn = *(const unsigned*)(KVp + (size_t)sjn * 256 + 128 + c2);
            unsigned en = *(const unsigned*)(EEc + (size_t)ejn * 128 + c2);

            float e0 = bf2f((unsigned short)(ec & 0xFFFFu));
            float e1 = bf2f((unsigned short)(ec >> 16));
            float k0 = bf2f((unsigned short)(kc & 0xFFFFu));
            float k1 = bf2f((unsigned short)(kc >> 16));
            float v0 = bf2f((unsigned short)(vc & 0xFFFFu));
            float v1 = bf2f((unsigned short)(vc >> 16));

            float t = q.x * (k0 + e0) + q.y * (k1 + e1);
            t += __shfl_xor(t, 1); t += __shfl_xor(t, 2);
            t += __shfl_xor(t, 4); t += __shfl_xor(t, 8);
            float alpha = t;   // ATT_SCALE pre-folded into Q
            float mn = fmaxf(m, alpha);
            float r = __expf(m - mn);
            float p = __expf(alpha - mn);
            s = s * r + p;
            a0 = a0 * r + p * (v0 + e0);
            a1 = a1 * r + p * (v1 + e1);
            m = mn;
            kc = kn; vc = vn; ec = en;
        }
        float inv = 1.f / (s + 1e-16f);
        float2 h = *(const float2*)(Hskip + (size_t)d * OUTF + c2);
        float2 o;
        o.x = a0 * inv + h.x;
        o.y = a1 * inv + h.y;
        *(float2*)(Out + (size_t)d * OUTF + c2) = o;
    }
}

extern "C" void kernel_launch(void* const* d_in, const int* in_sizes, int n_in,
                              void* d_out, int out_size, void* d_ws, size_t ws_size,
                              hipStream_t stream) {
    const float* x    = (const float*)d_in[0];
    const int*   ei   = (const int*)d_in[1];
    const float* ea   = (const float*)d_in[2];
    const float* emb  = (const float*)d_in[3];
    const float* w1q  = (const float*)d_in[4];  const float* b1q = (const float*)d_in[5];
    const float* w1k  = (const float*)d_in[6];  const float* b1k = (const float*)d_in[7];
    const float* w1v  = (const float*)d_in[8];  const float* b1v = (const float*)d_in[9];
    const float* w1e  = (const float*)d_in[10];
    const float* w1s  = (const float*)d_in[11]; const float* b1s = (const float*)d_in[12];
    const float* w2q  = (const float*)d_in[13]; const float* b2q = (const float*)d_in[14];
    const float* w2k  = (const float*)d_in[15]; const float* b2k = (const float*)d_in[16];
    const float* w2v  = (const float*)d_in[17]; const float* b2v = (const float*)d_in[18];
    const float* w2e  = (const float*)d_in[19];
    const float* w2s  = (const float*)d_in[20]; const float* b2s = (const float*)d_in[21];

    const int* srcI = ei;
    const int* dstI = ei + NE;

    float* Q = (float*)d_ws;                                        // N x 128 f32 (pre-scaled)
    unsigned short* KV = (unsigned short*)(Q + (size_t)NN * OUTF);  // N x 256 bf16 [K|V]
    float* H = (float*)(KV + (size_t)NN * 256);                     // N x 128 f32
    unsigned short* EE1 = (unsigned short*)(H + (size_t)NN * OUTF); // E x 128 bf16
    unsigned short* EE2 = EE1 + (size_t)NE * 128;                   // E x 128 bf16
    int* csr_src   = (int*)(EE2 + (size_t)NE * 128);
    int* csr_eid   = csr_src + NE;
    int* row_start = csr_eid + NE;            // N+1
    int* cursor    = row_start + NN + 1;
    int* cnt       = cursor + NN;
    int* S1        = cnt + NN;
    int* bsum      = S1 + NN;
    int* boff      = bsum + NSCANB;
    unsigned short* WT1  = (unsigned short*)(boff + NSCANB + 1);
    unsigned short* WT2  = WT1 + 512 * KPAD;
    unsigned short* WmT1 = WT2 + 512 * KPAD;
    unsigned short* WmT2 = WmT1 + OUTF * KPAD;
    float* bias1 = (float*)(WmT2 + OUTF * KPAD);
    float* bias2 = bias1 + 512;

    prep_weights<<<128, 256, 0, stream>>>(w1q, w1k, w1v, w1s, w2q, w2k, w2v, w2s,
                                          w1e, w2e, emb,
                                          b1q, b1k, b1v, b1s, b2q, b2k, b2v, b2s,
                                          WT1, WT2, WmT1, WmT2, bias1, bias2);
    hipMemsetAsync(cnt, 0, (size_t)NN * sizeof(int), stream);
    hist_kernel<<<NE / 256, 256, 0, stream>>>(dstI, cnt);
    scan1<<<NSCANB, 256, 0, stream>>>(cnt, S1, bsum);
    scan2<<<1, 512, 0, stream>>>(bsum, boff);
    scan3<<<NSCANB, 256, 0, stream>>>(S1, boff, cnt, row_start, cursor);
    scatter_csr<<<NE / 256, 256, 0, stream>>>(srcI, dstI, cursor, csr_src, csr_eid);

    int ngrid = ((NN + 127) / 128) * 4;   // 782 row-tiles x 4 col-blocks = 3128
    int egrid = NE / 64;                  // 10000

    // ---- node features L1 + fused dual-layer edge GEMM (EA read once) ----
    node_mfma<<<ngrid, 256, 0, stream>>>(x, K1, K1, 0, NN, WT1, bias1, Q, KV, H);
    edge_mfma_dual<<<egrid, 256, 0, stream>>>(ea, WmT1, WmT2, EE1, EE2);
    attn_node<<<2048, 256, 0, stream>>>(Q, KV, EE1, row_start, csr_src, csr_eid, H, H);

    // ---- layer 2 ----
    node_mfma<<<ngrid, 256, 0, stream>>>(H, OUTF, OUTF, 1, NN, WT2, bias2, Q, KV, (float*)d_out);
    attn_node<<<2048, 256, 0, stream>>>(Q, KV, EE2, row_start, csr_src, csr_eid, (float*)d_out, (float*)d_out);
}

// Round 14
// 1061.068 us; speedup vs baseline: 1.2768x; 1.0582x over previous
//
#include <hip/hip_runtime.h>

#define NN 100000
#define NE 640000
#define OUTF 128
#define K1 100
#define KE 118
#define KPAD 128
#define ASTR 136              // padded LDS row stride (ushorts)
#define ATT_SCALE 0.17677669529663687f
#define NSCANB 391            // ceil(NN/256)

typedef __attribute__((ext_vector_type(8))) short short8;
typedef __attribute__((ext_vector_type(4))) float f32x4;

__device__ __forceinline__ unsigned short f2bf(float f) {
    unsigned u = __float_as_uint(f);
    u += 0x7FFFu + ((u >> 16) & 1u);   // RNE
    return (unsigned short)(u >> 16);
}
__device__ __forceinline__ float bf2f(unsigned short h) {
    return __uint_as_float(((unsigned)h) << 16);
}

// ---------- prep: transposed bf16 weights [col][k]; WmT rows 118-121 = one-hot etype tables ----------
__global__ void prep_weights(
    const float* __restrict__ w1q, const float* __restrict__ w1k,
    const float* __restrict__ w1v, const float* __restrict__ w1s,
    const float* __restrict__ w2q, const float* __restrict__ w2k,
    const float* __restrict__ w2v, const float* __restrict__ w2s,
    const float* __restrict__ we1, const float* __restrict__ we2,
    const float* __restrict__ emb,
    const float* __restrict__ b1q, const float* __restrict__ b1k,
    const float* __restrict__ b1v, const float* __restrict__ b1s,
    const float* __restrict__ b2q, const float* __restrict__ b2k,
    const float* __restrict__ b2v, const float* __restrict__ b2s,
    unsigned short* __restrict__ WT1, unsigned short* __restrict__ WT2,
    unsigned short* __restrict__ WmT1, unsigned short* __restrict__ WmT2,
    float* __restrict__ bias1, float* __restrict__ bias2)
{
    int idx = blockIdx.x * blockDim.x + threadIdx.x;
    int stride = gridDim.x * blockDim.x;
    for (int i = idx; i < 512 * KPAD; i += stride) {
        int col = i >> 7, k = i & 127;
        int which = col >> 7, c = col & 127;
        const float* s1 = (which == 0) ? w1q : (which == 1) ? w1k : (which == 2) ? w1v : w1s;
        const float* s2 = (which == 0) ? w2q : (which == 1) ? w2k : (which == 2) ? w2v : w2s;
        float v1 = (k < K1) ? s1[k * OUTF + c] : 0.f;
        float v2 = s2[k * OUTF + c];
        WT1[i] = f2bf(v1); WT2[i] = f2bf(v2);
    }
    for (int i = idx; i < OUTF * KPAD; i += stride) {
        int col = i >> 7, k = i & 127;
        float v1 = 0.f, v2 = 0.f;
        if (k < 3)                 { v1 = we1[k * OUTF + col];       v2 = we2[k * OUTF + col]; }
        else if (k >= 4 && k < KE) { v1 = we1[(k - 1) * OUTF + col]; v2 = we2[(k - 1) * OUTF + col]; }
        else if (k >= KE && k < KE + 4) {
            int t = k - KE;
            #pragma unroll
            for (int r = 0; r < 8; r++) {
                float ev = emb[t * 8 + r];
                v1 += ev * we1[(117 + r) * OUTF + col];
                v2 += ev * we2[(117 + r) * OUTF + col];
            }
        }
        WmT1[i] = f2bf(v1); WmT2[i] = f2bf(v2);
    }
    for (int i = idx; i < 512; i += stride) {
        int which = i >> 7, c = i & 127;
        const float* sb1 = (which == 0) ? b1q : (which == 1) ? b1k : (which == 2) ? b1v : b1s;
        const float* sb2 = (which == 0) ? b2q : (which == 1) ? b2k : (which == 2) ? b2v : b2s;
        bias1[i] = sb1[c]; bias2[i] = sb2[c];
    }
}

// ---------- CSR build ----------
__global__ void hist_kernel(const int* __restrict__ dstI, int* __restrict__ cnt) {
    int e = blockIdx.x * 256 + threadIdx.x;
    if (e < NE) atomicAdd(&cnt[dstI[e]], 1);
}
__global__ void scan1(const int* __restrict__ cnt, int* __restrict__ S1, int* __restrict__ bsum) {
    __shared__ int sd[256];
    int t = blockIdx.x * 256 + threadIdx.x;
    sd[threadIdx.x] = (t < NN) ? cnt[t] : 0;
    __syncthreads();
    for (int off = 1; off < 256; off <<= 1) {
        int x = (threadIdx.x >= off) ? sd[threadIdx.x - off] : 0;
        __syncthreads();
        sd[threadIdx.x] += x;
        __syncthreads();
    }
    if (t < NN) S1[t] = sd[threadIdx.x];
    if (threadIdx.x == 255) bsum[blockIdx.x] = sd[255];
}
__global__ void scan2(const int* __restrict__ bsum, int* __restrict__ boff) {
    __shared__ int sd[512];
    int t = threadIdx.x;
    sd[t] = (t < NSCANB) ? bsum[t] : 0;
    __syncthreads();
    for (int off = 1; off < 512; off <<= 1) {
        int x = (t >= off) ? sd[t - off] : 0;
        __syncthreads();
        sd[t] += x;
        __syncthreads();
    }
    if (t < NSCANB) boff[t] = (t == 0) ? 0 : sd[t - 1];
}
__global__ void scan3(const int* __restrict__ S1, const int* __restrict__ boff,
                      const int* __restrict__ cnt,
                      int* __restrict__ row_start, int* __restrict__ cursor) {
    int t = blockIdx.x * 256 + threadIdx.x;
    if (t < NN) {
        int incl = S1[t] + boff[t >> 8];
        row_start[t + 1] = incl;
        cursor[t] = incl - cnt[t];
        if (t == 0) row_start[0] = 0;
    }
}
__global__ void scatter_csr(const int* __restrict__ srcI, const int* __restrict__ dstI,
                            int* __restrict__ cursor,
                            int* __restrict__ csr_src, int* __restrict__ csr_eid) {
    int e = blockIdx.x * 256 + threadIdx.x;
    if (e < NE) {
        int j = atomicAdd(&cursor[dstI[e]], 1);
        csr_src[j] = srcI[e];
        csr_eid[j] = e;
    }
}

// ---------- node GEMM, one 128-col block per block: coalesced LDS-staged epilogue ----------
// grid = ngrid*4; blockIdx = rowtile*4 + nb. nb: 0=Q(f32, pre-scaled) 1=K(bf16) 2=V(bf16) 3=H(f32)
__global__ __launch_bounds__(256) void node_mfma(
    const float* __restrict__ X, int ldx, int Kdim, int relu, int n,
    const unsigned short* __restrict__ WT, const float* __restrict__ bias,
    float* __restrict__ Qp, unsigned short* __restrict__ KVp, float* __restrict__ Hp)
{
    __shared__ unsigned short Alds[128][ASTR];     // A tile; reused as output staging after MFMA
    int tid = threadIdx.x;
    int rowbase = (blockIdx.x >> 2) * 128;
    int nb = blockIdx.x & 3;

    for (int idx = tid; idx < 128 * 68; idx += 256) {
        int r = idx / 68, kv = idx % 68;
        int k = kv * 2;
        float2 v = make_float2(0.f, 0.f);
        int gr = rowbase + r;
        if (gr < n && k < Kdim) v = *(const float2*)(X + (size_t)gr * ldx + k);
        if (relu) { v.x = fmaxf(v.x, 0.f); v.y = fmaxf(v.y, 0.f); }
        unsigned pv = (unsigned)f2bf(v.x) | ((unsigned)f2bf(v.y) << 16);
        *(unsigned*)&Alds[r][k] = pv;
    }
    __syncthreads();

    int lane = tid & 63, wid = tid >> 6;
    int wm = wid >> 1, wn = wid & 1;
    int l15 = lane & 15, l4 = lane >> 4;

    f32x4 acc[4][4];
    #pragma unroll
    for (int mf = 0; mf < 4; mf++)
        #pragma unroll
        for (int nf = 0; nf < 4; nf++)
            acc[mf][nf] = (f32x4){0.f, 0.f, 0.f, 0.f};

    const unsigned short* wbase = WT + (size_t)(nb * 128 + wn * 64 + l15) * KPAD + l4 * 8;
    #pragma unroll
    for (int ks = 0; ks < 4; ks++) {
        short8 af[4], bfr[4];
        #pragma unroll
        for (int mf = 0; mf < 4; mf++)
            af[mf] = *(const short8*)&Alds[wm * 64 + mf * 16 + l15][ks * 32 + l4 * 8];
        #pragma unroll
        for (int nf = 0; nf < 4; nf++)
            bfr[nf] = *(const short8*)(wbase + (size_t)nf * 16 * KPAD + ks * 32);
        #pragma unroll
        for (int mf = 0; mf < 4; mf++)
            #pragma unroll
            for (int nf = 0; nf < 4; nf++)
                acc[mf][nf] = __builtin_amdgcn_mfma_f32_16x16x32_bf16(af[mf], bfr[nf], acc[mf][nf], 0, 0, 0);
    }
    __syncthreads();   // A tile dead; reuse LDS for output staging

    if (nb == 1 || nb == 2) {
        // --- bf16 K/V: one 128x128 ushort tile, uint4 stores (full 256B rows) ---
        #pragma unroll
        for (int nf = 0; nf < 4; nf++) {
            int col = wn * 64 + nf * 16 + l15;
            float bv = bias[nb * 128 + col];
            #pragma unroll
            for (int mf = 0; mf < 4; mf++)
                #pragma unroll
                for (int rr = 0; rr < 4; rr++)
                    Alds[wm * 64 + mf * 16 + l4 * 4 + rr][col] = f2bf(acc[mf][nf][rr] + bv);
        }
        __syncthreads();
        int off = (nb == 1) ? 0 : 128;
        #pragma unroll
        for (int it = 0; it < 8; it++) {
            int idx = it * 256 + tid;
            int row = idx >> 4, c8 = (idx & 15) * 8;
            if (rowbase + row < n) {
                uint4 v = *(const uint4*)&Alds[row][c8];
                *(uint4*)(KVp + (size_t)(rowbase + row) * 256 + off + c8) = v;
            }
        }
    } else {
        // --- f32 Q/H: two 64-col half tiles ([128][68] f32 == Alds footprint), float4 stores ---
        float* Yp = (nb == 0) ? Qp : Hp;
        float scale = (nb == 0) ? ATT_SCALE : 1.f;
        float (*Sf)[68] = (float (*)[68])Alds;
        #pragma unroll
        for (int h = 0; h < 2; h++) {
            if (wn == h) {
                #pragma unroll
                for (int nf = 0; nf < 4; nf++) {
                    int col = wn * 64 + nf * 16 + l15;
                    float bv = bias[nb * 128 + col];
                    #pragma unroll
                    for (int mf = 0; mf < 4; mf++)
                        #pragma unroll
                        for (int rr = 0; rr < 4; rr++)
                            Sf[wm * 64 + mf * 16 + l4 * 4 + rr][nf * 16 + l15] =
                                (acc[mf][nf][rr] + bv) * scale;
                }
            }
            __syncthreads();
            #pragma unroll
            for (int it = 0; it < 8; it++) {
                int idx = it * 256 + tid;
                int row = idx >> 4, c4 = (idx & 15) * 4;
                if (rowbase + row < n) {
                    float4 v = *(const float4*)&Sf[row][c4];
                    *(float4*)(Yp + (size_t)(rowbase + row) * OUTF + h * 64 + c4) = v;
                }
            }
            if (h == 0) __syncthreads();
        }
    }
}

// ---------- fused dual-layer edge GEMM: ZERO barriers, ZERO staging ----------
// A-fragments loaded directly from fp32 EA (16x float2 per lane), bf16-converted in-register,
// one-hot etype patched in-register; af reused for both layers; wave-private LDS transpose;
// linear EE1/EE2 stores. 64-row tile, 256 threads / 4 waves / 16 rows per wave.
__global__ __launch_bounds__(256) void edge_mfma_fused(
    const float* __restrict__ EA,
    const unsigned short* __restrict__ WmT1, const unsigned short* __restrict__ WmT2,
    unsigned short* __restrict__ EE1, unsigned short* __restrict__ EE2)
{
    __shared__ unsigned short Tlds[64][ASTR];   // transpose buffer only (wave-private quadrants)
    int tid = threadIdx.x;
    int lane = tid & 63, w = tid >> 6;
    int e0 = blockIdx.x * 64;
    int l15 = lane & 15, l4 = lane >> 4;
    int rbase = w * 16;
    const float* rp = EA + (size_t)(e0 + rbase + l15) * KE;

    int et = (int)rp[3];
    int oh = KE + et;                 // one-hot col 118..121 (lives in ks==3 chunk)

    short8 af[4];
    #pragma unroll
    for (int ks = 0; ks < 4; ks++) {
        int cbase = ks * 32 + l4 * 8;
        float f[8];
        #pragma unroll
        for (int h = 0; h < 4; h++) {
            int c = cbase + h * 2;                 // always even; row base 8B-aligned
            float2 t = make_float2(0.f, 0.f);
            if (c + 2 <= KE) t = *(const float2*)(rp + c);
            f[h * 2] = t.x; f[h * 2 + 1] = t.y;
        }
        #pragma unroll
        for (int j = 0; j < 8; j++) {
            int col = cbase + j;
            float fv = (col == 3) ? 0.f : f[j];    // col 3 = etype -> zero
            unsigned short bs = f2bf(fv);
            if (ks == 3 && col == oh) bs = 0x3F80; // one-hot bf16 1.0
            af[ks][j] = bs;
        }
    }

    auto do_layer = [&](const unsigned short* __restrict__ WmT, unsigned short* __restrict__ EEc) {
        f32x4 acc[8];
        #pragma unroll
        for (int nf = 0; nf < 8; nf++) acc[nf] = (f32x4){0.f, 0.f, 0.f, 0.f};

        #pragma unroll
        for (int ks = 0; ks < 4; ks++) {
            short8 bfr[8];
            #pragma unroll
            for (int nf = 0; nf < 8; nf++)
                bfr[nf] = *(const short8*)(WmT + (size_t)(nf * 16 + l15) * KPAD + ks * 32 + l4 * 8);
            #pragma unroll
            for (int nf = 0; nf < 8; nf++)
                acc[nf] = __builtin_amdgcn_mfma_f32_16x16x32_bf16(af[ks], bfr[nf], acc[nf], 0, 0, 0);
        }
        // wave-private transpose through own LDS rows (no barrier), coalesced linear store
        #pragma unroll
        for (int nf = 0; nf < 8; nf++)
            #pragma unroll
            for (int rr = 0; rr < 4; rr++)
                Tlds[rbase + l4 * 4 + rr][nf * 16 + l15] = f2bf(acc[nf][rr]);
        #pragma unroll
        for (int it = 0; it < 4; it++) {
            int t2 = it * 64 + lane;
            int rid = t2 >> 4, c8 = (t2 & 15) * 8;   // rid spans [0,16) over it=0..3
            uint4 v = *(const uint4*)&Tlds[rbase + rid][c8];
            *(uint4*)(EEc + ((size_t)(e0 + rbase + rid)) * 128 + c8) = v;
        }
    };
    do_layer(WmT1, EE1);
    do_layer(WmT2, EE2);
}

// ---------- fused attn: one wave per dst, online softmax, 1-deep prefetch, EE gathered by eid ----------
__global__ __launch_bounds__(256) void attn_node(
    const float* __restrict__ Qp, const unsigned short* __restrict__ KVp,
    const unsigned short* __restrict__ EEc,
    const int* __restrict__ row_start, const int* __restrict__ csr_src,
    const int* __restrict__ csr_eid,
    const float* __restrict__ Hskip, float* __restrict__ Out)
{
    int lane = threadIdx.x & 63;
    int gw = (int)((blockIdx.x * (size_t)blockDim.x + threadIdx.x) >> 6);
    int nW = (gridDim.x * blockDim.x) >> 6;
    int c2 = lane * 2;

    for (int d = gw; d < NN; d += nW) {
        int rs = row_start[d], re = row_start[d + 1];
        float2 q = *(const float2*)(Qp + (size_t)d * OUTF + c2);
        float m = -3.4e38f, s = 0.f, a0 = 0.f, a1 = 0.f;

        int j0 = (rs < re) ? rs : 0;
        int sj = csr_src[j0];
        int ej = csr_eid[j0];
        unsigned kc = *(const unsigned*)(KVp + (size_t)sj * 256 + c2);
        unsigned vc = *(const unsigned*)(KVp + (size_t)sj * 256 + 128 + c2);
        unsigned ec = *(const unsigned*)(EEc + (size_t)ej * 128 + c2);

        for (int j = rs; j < re; j++) {
            int jn = (j + 1 < re) ? j + 1 : j;
            int sjn = csr_src[jn];
            int ejn = csr_eid[jn];
            unsigned kn = *(const unsigned*)(KVp + (size_t)sjn * 256 + c2);
            unsigned vn = *(const unsigned*)(KVp + (size_t)sjn * 256 + 128 + c2);
            unsigned en = *(const unsigned*)(EEc + (size_t)ejn * 128 + c2);

            float e0 = bf2f((unsigned short)(ec & 0xFFFFu));
            float e1 = bf2f((unsigned short)(ec >> 16));
            float k0 = bf2f((unsigned short)(kc & 0xFFFFu));
            float k1 = bf2f((unsigned short)(kc >> 16));
            float v0 = bf2f((unsigned short)(vc & 0xFFFFu));
            float v1 = bf2f((unsigned short)(vc >> 16));

            float t = q.x * (k0 + e0) + q.y * (k1 + e1);
            t += __shfl_xor(t, 1); t += __shfl_xor(t, 2);
            t += __shfl_xor(t, 4); t += __shfl_xor(t, 8);
            float alpha = t;   // ATT_SCALE pre-folded into Q
            float mn = fmaxf(m, alpha);
            float r = __expf(m - mn);
            float p = __expf(alpha - mn);
            s = s * r + p;
            a0 = a0 * r + p * (v0 + e0);
            a1 = a1 * r + p * (v1 + e1);
            m = mn;
            kc = kn; vc = vn; ec = en;
        }
        float inv = 1.f / (s + 1e-16f);
        float2 h = *(const float2*)(Hskip + (size_t)d * OUTF + c2);
        float2 o;
        o.x = a0 * inv + h.x;
        o.y = a1 * inv + h.y;
        *(float2*)(Out + (size_t)d * OUTF + c2) = o;
    }
}

extern "C" void kernel_launch(void* const* d_in, const int* in_sizes, int n_in,
                              void* d_out, int out_size, void* d_ws, size_t ws_size,
                              hipStream_t stream) {
    const float* x    = (const float*)d_in[0];
    const int*   ei   = (const int*)d_in[1];
    const float* ea   = (const float*)d_in[2];
    const float* emb  = (const float*)d_in[3];
    const float* w1q  = (const float*)d_in[4];  const float* b1q = (const float*)d_in[5];
    const float* w1k  = (const float*)d_in[6];  const float* b1k = (const float*)d_in[7];
    const float* w1v  = (const float*)d_in[8];  const float* b1v = (const float*)d_in[9];
    const float* w1e  = (const float*)d_in[10];
    const float* w1s  = (const float*)d_in[11]; const float* b1s = (const float*)d_in[12];
    const float* w2q  = (const float*)d_in[13]; const float* b2q = (const float*)d_in[14];
    const float* w2k  = (const float*)d_in[15]; const float* b2k = (const float*)d_in[16];
    const float* w2v  = (const float*)d_in[17]; const float* b2v = (const float*)d_in[18];
    const float* w2e  = (const float*)d_in[19];
    const float* w2s  = (const float*)d_in[20]; const float* b2s = (const float*)d_in[21];

    const int* srcI = ei;
    const int* dstI = ei + NE;

    float* Q = (float*)d_ws;                                        // N x 128 f32 (pre-scaled)
    unsigned short* KV = (unsigned short*)(Q + (size_t)NN * OUTF);  // N x 256 bf16 [K|V]
    float* H = (float*)(KV + (size_t)NN * 256);                     // N x 128 f32
    unsigned short* EE1 = (unsigned short*)(H + (size_t)NN * OUTF); // E x 128 bf16
    unsigned short* EE2 = EE1 + (size_t)NE * 128;                   // E x 128 bf16
    int* csr_src   = (int*)(EE2 + (size_t)NE * 128);
    int* csr_eid   = csr_src + NE;
    int* row_start = csr_eid + NE;            // N+1
    int* cursor    = row_start + NN + 1;
    int* cnt       = cursor + NN;
    int* S1        = cnt + NN;
    int* bsum      = S1 + NN;
    int* boff      = bsum + NSCANB;
    unsigned short* WT1  = (unsigned short*)(boff + NSCANB + 1);
    unsigned short* WT2  = WT1 + 512 * KPAD;
    unsigned short* WmT1 = WT2 + 512 * KPAD;
    unsigned short* WmT2 = WmT1 + OUTF * KPAD;
    float* bias1 = (float*)(WmT2 + OUTF * KPAD);
    float* bias2 = bias1 + 512;

    prep_weights<<<128, 256, 0, stream>>>(w1q, w1k, w1v, w1s, w2q, w2k, w2v, w2s,
                                          w1e, w2e, emb,
                                          b1q, b1k, b1v, b1s, b2q, b2k, b2v, b2s,
                                          WT1, WT2, WmT1, WmT2, bias1, bias2);
    hipMemsetAsync(cnt, 0, (size_t)NN * sizeof(int), stream);
    hist_kernel<<<NE / 256, 256, 0, stream>>>(dstI, cnt);
    scan1<<<NSCANB, 256, 0, stream>>>(cnt, S1, bsum);
    scan2<<<1, 512, 0, stream>>>(bsum, boff);
    scan3<<<NSCANB, 256, 0, stream>>>(S1, boff, cnt, row_start, cursor);
    scatter_csr<<<NE / 256, 256, 0, stream>>>(srcI, dstI, cursor, csr_src, csr_eid);

    int ngrid = ((NN + 127) / 128) * 4;   // 782 row-tiles x 4 col-blocks = 3128
    int egrid = NE / 64;                  // 10000

    // ---- node features L1 + fused dual-layer edge GEMM (EA read once, barrier-free) ----
    node_mfma<<<ngrid, 256, 0, stream>>>(x, K1, K1, 0, NN, WT1, bias1, Q, KV, H);
    edge_mfma_fused<<<egrid, 256, 0, stream>>>(ea, WmT1, WmT2, EE1, EE2);
    attn_node<<<2048, 256, 0, stream>>>(Q, KV, EE1, row_start, csr_src, csr_eid, H, H);

    // ---- layer 2 ----
    node_mfma<<<ngrid, 256, 0, stream>>>(H, OUTF, OUTF, 1, NN, WT2, bias2, Q, KV, (float*)d_out);
    attn_node<<<2048, 256, 0, stream>>>(Q, KV, EE2, row_start, csr_src, csr_eid, (float*)d_out, (float*)d_out);
}

// Round 15
// 994.138 us; speedup vs baseline: 1.3627x; 1.0673x over previous
//
#include <hip/hip_runtime.h>

#define NN 100000
#define NE 640000
#define OUTF 128
#define K1 100
#define KE 118
#define KPAD 128
#define ASTR 136              // padded LDS row stride (ushorts)
#define ATT_SCALE 0.17677669529663687f
#define NSCANB 391            // ceil(NN/256)
#define ETILES 5              // tiles per edge block (NE/64/2000)

typedef __attribute__((ext_vector_type(8))) short short8;
typedef __attribute__((ext_vector_type(4))) float f32x4;

__device__ __forceinline__ unsigned short f2bf(float f) {
    unsigned u = __float_as_uint(f);
    u += 0x7FFFu + ((u >> 16) & 1u);   // RNE
    return (unsigned short)(u >> 16);
}
__device__ __forceinline__ float bf2f(unsigned short h) {
    return __uint_as_float(((unsigned)h) << 16);
}

// ---------- prep: transposed bf16 weights [col][k]; WmT rows 118-121 = one-hot etype tables ----------
__global__ void prep_weights(
    const float* __restrict__ w1q, const float* __restrict__ w1k,
    const float* __restrict__ w1v, const float* __restrict__ w1s,
    const float* __restrict__ w2q, const float* __restrict__ w2k,
    const float* __restrict__ w2v, const float* __restrict__ w2s,
    const float* __restrict__ we1, const float* __restrict__ we2,
    const float* __restrict__ emb,
    const float* __restrict__ b1q, const float* __restrict__ b1k,
    const float* __restrict__ b1v, const float* __restrict__ b1s,
    const float* __restrict__ b2q, const float* __restrict__ b2k,
    const float* __restrict__ b2v, const float* __restrict__ b2s,
    unsigned short* __restrict__ WT1, unsigned short* __restrict__ WT2,
    unsigned short* __restrict__ WmT1, unsigned short* __restrict__ WmT2,
    float* __restrict__ bias1, float* __restrict__ bias2)
{
    int idx = blockIdx.x * blockDim.x + threadIdx.x;
    int stride = gridDim.x * blockDim.x;
    for (int i = idx; i < 512 * KPAD; i += stride) {
        int col = i >> 7, k = i & 127;
        int which = col >> 7, c = col & 127;
        const float* s1 = (which == 0) ? w1q : (which == 1) ? w1k : (which == 2) ? w1v : w1s;
        const float* s2 = (which == 0) ? w2q : (which == 1) ? w2k : (which == 2) ? w2v : w2s;
        float v1 = (k < K1) ? s1[k * OUTF + c] : 0.f;
        float v2 = s2[k * OUTF + c];
        WT1[i] = f2bf(v1); WT2[i] = f2bf(v2);
    }
    for (int i = idx; i < OUTF * KPAD; i += stride) {
        int col = i >> 7, k = i & 127;
        float v1 = 0.f, v2 = 0.f;
        if (k < 3)                 { v1 = we1[k * OUTF + col];       v2 = we2[k * OUTF + col]; }
        else if (k >= 4 && k < KE) { v1 = we1[(k - 1) * OUTF + col]; v2 = we2[(k - 1) * OUTF + col]; }
        else if (k >= KE && k < KE + 4) {
            int t = k - KE;
            #pragma unroll
            for (int r = 0; r < 8; r++) {
                float ev = emb[t * 8 + r];
                v1 += ev * we1[(117 + r) * OUTF + col];
                v2 += ev * we2[(117 + r) * OUTF + col];
            }
        }
        WmT1[i] = f2bf(v1); WmT2[i] = f2bf(v2);
    }
    for (int i = idx; i < 512; i += stride) {
        int which = i >> 7, c = i & 127;
        const float* sb1 = (which == 0) ? b1q : (which == 1) ? b1k : (which == 2) ? b1v : b1s;
        const float* sb2 = (which == 0) ? b2q : (which == 1) ? b2k : (which == 2) ? b2v : b2s;
        bias1[i] = sb1[c]; bias2[i] = sb2[c];
    }
}

// ---------- CSR build ----------
__global__ void hist_kernel(const int* __restrict__ dstI, int* __restrict__ cnt) {
    int e = blockIdx.x * 256 + threadIdx.x;
    if (e < NE) atomicAdd(&cnt[dstI[e]], 1);
}
__global__ void scan1(const int* __restrict__ cnt, int* __restrict__ S1, int* __restrict__ bsum) {
    __shared__ int sd[256];
    int t = blockIdx.x * 256 + threadIdx.x;
    sd[threadIdx.x] = (t < NN) ? cnt[t] : 0;
    __syncthreads();
    for (int off = 1; off < 256; off <<= 1) {
        int x = (threadIdx.x >= off) ? sd[threadIdx.x - off] : 0;
        __syncthreads();
        sd[threadIdx.x] += x;
        __syncthreads();
    }
    if (t < NN) S1[t] = sd[threadIdx.x];
    if (threadIdx.x == 255) bsum[blockIdx.x] = sd[255];
}
__global__ void scan2(const int* __restrict__ bsum, int* __restrict__ boff) {
    __shared__ int sd[512];
    int t = threadIdx.x;
    sd[t] = (t < NSCANB) ? bsum[t] : 0;
    __syncthreads();
    for (int off = 1; off < 512; off <<= 1) {
        int x = (t >= off) ? sd[t - off] : 0;
        __syncthreads();
        sd[t] += x;
        __syncthreads();
    }
    if (t < NSCANB) boff[t] = (t == 0) ? 0 : sd[t - 1];
}
__global__ void scan3(const int* __restrict__ S1, const int* __restrict__ boff,
                      const int* __restrict__ cnt,
                      int* __restrict__ row_start, int* __restrict__ cursor) {
    int t = blockIdx.x * 256 + threadIdx.x;
    if (t < NN) {
        int incl = S1[t] + boff[t >> 8];
        row_start[t + 1] = incl;
        cursor[t] = incl - cnt[t];
        if (t == 0) row_start[0] = 0;
    }
}
__global__ void scatter_csr(const int* __restrict__ srcI, const int* __restrict__ dstI,
                            int* __restrict__ cursor,
                            int* __restrict__ csr_src, int* __restrict__ csr_eid) {
    int e = blockIdx.x * 256 + threadIdx.x;
    if (e < NE) {
        int j = atomicAdd(&cursor[dstI[e]], 1);
        csr_src[j] = srcI[e];
        csr_eid[j] = e;
    }
}

// ---------- node GEMM, one 128-col block per block: coalesced LDS-staged epilogue ----------
// grid = ngrid*4; blockIdx = rowtile*4 + nb. nb: 0=Q(f32, pre-scaled) 1=K(bf16) 2=V(bf16) 3=H(f32)
__global__ __launch_bounds__(256) void node_mfma(
    const float* __restrict__ X, int ldx, int Kdim, int relu, int n,
    const unsigned short* __restrict__ WT, const float* __restrict__ bias,
    float* __restrict__ Qp, unsigned short* __restrict__ KVp, float* __restrict__ Hp)
{
    __shared__ unsigned short Alds[128][ASTR];     // A tile; reused as output staging after MFMA
    int tid = threadIdx.x;
    int rowbase = (blockIdx.x >> 2) * 128;
    int nb = blockIdx.x & 3;

    for (int idx = tid; idx < 128 * 68; idx += 256) {
        int r = idx / 68, kv = idx % 68;
        int k = kv * 2;
        float2 v = make_float2(0.f, 0.f);
        int gr = rowbase + r;
        if (gr < n && k < Kdim) v = *(const float2*)(X + (size_t)gr * ldx + k);
        if (relu) { v.x = fmaxf(v.x, 0.f); v.y = fmaxf(v.y, 0.f); }
        unsigned pv = (unsigned)f2bf(v.x) | ((unsigned)f2bf(v.y) << 16);
        *(unsigned*)&Alds[r][k] = pv;
    }
    __syncthreads();

    int lane = tid & 63, wid = tid >> 6;
    int wm = wid >> 1, wn = wid & 1;
    int l15 = lane & 15, l4 = lane >> 4;

    f32x4 acc[4][4];
    #pragma unroll
    for (int mf = 0; mf < 4; mf++)
        #pragma unroll
        for (int nf = 0; nf < 4; nf++)
            acc[mf][nf] = (f32x4){0.f, 0.f, 0.f, 0.f};

    const unsigned short* wbase = WT + (size_t)(nb * 128 + wn * 64 + l15) * KPAD + l4 * 8;
    #pragma unroll
    for (int ks = 0; ks < 4; ks++) {
        short8 af[4], bfr[4];
        #pragma unroll
        for (int mf = 0; mf < 4; mf++)
            af[mf] = *(const short8*)&Alds[wm * 64 + mf * 16 + l15][ks * 32 + l4 * 8];
        #pragma unroll
        for (int nf = 0; nf < 4; nf++)
            bfr[nf] = *(const short8*)(wbase + (size_t)nf * 16 * KPAD + ks * 32);
        #pragma unroll
        for (int mf = 0; mf < 4; mf++)
            #pragma unroll
            for (int nf = 0; nf < 4; nf++)
                acc[mf][nf] = __builtin_amdgcn_mfma_f32_16x16x32_bf16(af[mf], bfr[nf], acc[mf][nf], 0, 0, 0);
    }
    __syncthreads();   // A tile dead; reuse LDS for output staging

    if (nb == 1 || nb == 2) {
        // --- bf16 K/V: one 128x128 ushort tile, uint4 stores (full 256B rows) ---
        #pragma unroll
        for (int nf = 0; nf < 4; nf++) {
            int col = wn * 64 + nf * 16 + l15;
            float bv = bias[nb * 128 + col];
            #pragma unroll
            for (int mf = 0; mf < 4; mf++)
                #pragma unroll
                for (int rr = 0; rr < 4; rr++)
                    Alds[wm * 64 + mf * 16 + l4 * 4 + rr][col] = f2bf(acc[mf][nf][rr] + bv);
        }
        __syncthreads();
        int off = (nb == 1) ? 0 : 128;
        #pragma unroll
        for (int it = 0; it < 8; it++) {
            int idx = it * 256 + tid;
            int row = idx >> 4, c8 = (idx & 15) * 8;
            if (rowbase + row < n) {
                uint4 v = *(const uint4*)&Alds[row][c8];
                *(uint4*)(KVp + (size_t)(rowbase + row) * 256 + off + c8) = v;
            }
        }
    } else {
        // --- f32 Q/H: two 64-col half tiles ([128][68] f32 == Alds footprint), float4 stores ---
        float* Yp = (nb == 0) ? Qp : Hp;
        float scale = (nb == 0) ? ATT_SCALE : 1.f;
        float (*Sf)[68] = (float (*)[68])Alds;
        #pragma unroll
        for (int h = 0; h < 2; h++) {
            if (wn == h) {
                #pragma unroll
                for (int nf = 0; nf < 4; nf++) {
                    int col = wn * 64 + nf * 16 + l15;
                    float bv = bias[nb * 128 + col];
                    #pragma unroll
                    for (int mf = 0; mf < 4; mf++)
                        #pragma unroll
                        for (int rr = 0; rr < 4; rr++)
                            Sf[wm * 64 + mf * 16 + l4 * 4 + rr][nf * 16 + l15] =
                                (acc[mf][nf][rr] + bv) * scale;
                }
            }
            __syncthreads();
            #pragma unroll
            for (int it = 0; it < 8; it++) {
                int idx = it * 256 + tid;
                int row = idx >> 4, c4 = (idx & 15) * 4;
                if (rowbase + row < n) {
                    float4 v = *(const float4*)&Sf[row][c4];
                    *(float4*)(Yp + (size_t)(rowbase + row) * OUTF + h * 64 + c4) = v;
                }
            }
            if (h == 0) __syncthreads();
        }
    }
}

// ---------- fused dual-layer edge GEMM: 5 tiles per block, software-pipelined prefetch ----------
// Zero barriers. A-fragments direct from fp32 EA; raw loads of tile t+1 issued between layer 1
// and layer 2 of tile t so HBM latency hides under MFMA/transpose/stores. 64-row tiles, 4 waves.
__global__ __launch_bounds__(256) void edge_mfma_fused(
    const float* __restrict__ EA,
    const unsigned short* __restrict__ WmT1, const unsigned short* __restrict__ WmT2,
    unsigned short* __restrict__ EE1, unsigned short* __restrict__ EE2)
{
    __shared__ unsigned short Tlds[64][ASTR];   // transpose buffer (wave-private quadrants)
    int tid = threadIdx.x;
    int lane = tid & 63, w = tid >> 6;
    int l15 = lane & 15, l4 = lane >> 4;
    int rbase = w * 16;
    int tile0 = blockIdx.x * ETILES;

    // issue the 16 float2 raw loads (+ etype) for a tile
    auto load_raw = [&](int tile, float2* f, float& etf) {
        const float* rp = EA + (size_t)(tile * 64 + rbase + l15) * KE;
        etf = rp[3];
        #pragma unroll
        for (int ks = 0; ks < 4; ks++) {
            int cbase = ks * 32 + l4 * 8;
            #pragma unroll
            for (int h = 0; h < 4; h++) {
                int c = cbase + h * 2;                 // even; row base 8B-aligned
                float2 t = make_float2(0.f, 0.f);
                if (c + 2 <= KE) t = *(const float2*)(rp + c);
                f[ks * 4 + h] = t;
            }
        }
    };
    // convert raw fp32 -> bf16 fragments, zero etype col, patch one-hot
    auto convert = [&](const float2* f, float etf, short8* af) {
        int oh = KE + (int)etf;                        // one-hot col 118..121 (ks==3 chunk)
        #pragma unroll
        for (int ks = 0; ks < 4; ks++) {
            int cbase = ks * 32 + l4 * 8;
            #pragma unroll
            for (int j = 0; j < 8; j++) {
                int col = cbase + j;
                float fv = (j & 1) ? f[ks * 4 + (j >> 1)].y : f[ks * 4 + (j >> 1)].x;
                if (col == 3) fv = 0.f;                // col 3 = etype -> zero
                unsigned short bs = f2bf(fv);
                if (ks == 3 && col == oh) bs = 0x3F80; // one-hot bf16 1.0
                af[ks][j] = bs;
            }
        }
    };
    auto do_layer = [&](const unsigned short* __restrict__ WmT, unsigned short* __restrict__ EEc,
                        int e0, const short8* af) {
        f32x4 acc[8];
        #pragma unroll
        for (int nf = 0; nf < 8; nf++) acc[nf] = (f32x4){0.f, 0.f, 0.f, 0.f};

        #pragma unroll
        for (int ks = 0; ks < 4; ks++) {
            short8 bfr[8];
            #pragma unroll
            for (int nf = 0; nf < 8; nf++)
                bfr[nf] = *(const short8*)(WmT + (size_t)(nf * 16 + l15) * KPAD + ks * 32 + l4 * 8);
            #pragma unroll
            for (int nf = 0; nf < 8; nf++)
                acc[nf] = __builtin_amdgcn_mfma_f32_16x16x32_bf16(af[ks], bfr[nf], acc[nf], 0, 0, 0);
        }
        // wave-private transpose through own LDS rows (no barrier), coalesced linear store
        #pragma unroll
        for (int nf = 0; nf < 8; nf++)
            #pragma unroll
            for (int rr = 0; rr < 4; rr++)
                Tlds[rbase + l4 * 4 + rr][nf * 16 + l15] = f2bf(acc[nf][rr]);
        #pragma unroll
        for (int it = 0; it < 4; it++) {
            int t2 = it * 64 + lane;
            int rid = t2 >> 4, c8 = (t2 & 15) * 8;     // rid spans [0,16) over it=0..3
            uint4 v = *(const uint4*)&Tlds[rbase + rid][c8];
            *(uint4*)(EEc + ((size_t)(e0 + rbase + rid)) * 128 + c8) = v;
        }
    };

    float2 fraw[16];
    float etf;
    short8 af[4];
    load_raw(tile0, fraw, etf);
    convert(fraw, etf, af);

    #pragma unroll
    for (int t = 0; t < ETILES; t++) {
        int e0 = (tile0 + t) * 64;
        do_layer(WmT1, EE1, e0, af);
        float2 fnext[16];
        float etn = 0.f;
        if (t + 1 < ETILES) load_raw(tile0 + t + 1, fnext, etn);   // in flight under layer 2
        do_layer(WmT2, EE2, e0, af);
        if (t + 1 < ETILES) convert(fnext, etn, af);
    }
}

// ---------- fused attn: one wave per dst, online softmax, 2-deep index prefetch, zero atomics ----------
__global__ __launch_bounds__(256) void attn_node(
    const float* __restrict__ Qp, const unsigned short* __restrict__ KVp,
    const unsigned short* __restrict__ EEc,
    const int* __restrict__ row_start, const int* __restrict__ csr_src,
    const int* __restrict__ csr_eid,
    const float* __restrict__ Hskip, float* __restrict__ Out)
{
    int lane = threadIdx.x & 63;
    int gw = (int)((blockIdx.x * (size_t)blockDim.x + threadIdx.x) >> 6);
    int nW = (gridDim.x * blockDim.x) >> 6;
    int c2 = lane * 2;

    for (int d = gw; d < NN; d += nW) {
        int rs = row_start[d], re = row_start[d + 1];
        float2 q = *(const float2*)(Qp + (size_t)d * OUTF + c2);
        float m = -3.4e38f, s = 0.f, a0 = 0.f, a1 = 0.f;

        int j0 = (rs < re) ? rs : 0;
        int jlast = (rs < re) ? re - 1 : 0;
        int sjA = csr_src[j0], ejA = csr_eid[j0];
        int j1 = (j0 + 1 <= jlast) ? j0 + 1 : jlast;
        int sjB = csr_src[j1], ejB = csr_eid[j1];       // indices for j+1
        unsigned kc = *(const unsigned*)(KVp + (size_t)sjA * 256 + c2);
        unsigned vc = *(const unsigned*)(KVp + (size_t)sjA * 256 + 128 + c2);
        unsigned ec = *(const unsigned*)(EEc + (size_t)ejA * 128 + c2);

        for (int j = rs; j < re; j++) {
            // data gathers for j+1 (indices already resident)
            unsigned kn = *(const unsigned*)(KVp + (size_t)sjB * 256 + c2);
            unsigned vn = *(const unsigned*)(KVp + (size_t)sjB * 256 + 128 + c2);
            unsigned en = *(const unsigned*)(EEc + (size_t)ejB * 128 + c2);
            // index prefetch for j+2
            int j2 = (j + 2 <= jlast) ? j + 2 : jlast;
            int sjC = csr_src[j2], ejC = csr_eid[j2];

            float e0 = bf2f((unsigned short)(ec & 0xFFFFu));
            float e1 = bf2f((unsigned short)(ec >> 16));
            float k0 = bf2f((unsigned short)(kc & 0xFFFFu));
            float k1 = bf2f((unsigned short)(kc >> 16));
            float v0 = bf2f((unsigned short)(vc & 0xFFFFu));
            float v1 = bf2f((unsigned short)(vc >> 16));

            float t = q.x * (k0 + e0) + q.y * (k1 + e1);
            t += __shfl_xor(t, 1); t += __shfl_xor(t, 2);
            t += __shfl_xor(t, 4); t += __shfl_xor(t, 8);
            float alpha = t;   // ATT_SCALE pre-folded into Q
            float mn = fmaxf(m, alpha);
            float r = __expf(m - mn);
            float p = __expf(alpha - mn);
            s = s * r + p;
            a0 = a0 * r + p * (v0 + e0);
            a1 = a1 * r + p * (v1 + e1);
            m = mn;
            kc = kn; vc = vn; ec = en;
            sjB = sjC; ejB = ejC;
        }
        float inv = 1.f / (s + 1e-16f);
        float2 h = *(const float2*)(Hskip + (size_t)d * OUTF + c2);
        float2 o;
        o.x = a0 * inv + h.x;
        o.y = a1 * inv + h.y;
        *(float2*)(Out + (size_t)d * OUTF + c2) = o;
    }
}

extern "C" void kernel_launch(void* const* d_in, const int* in_sizes, int n_in,
                              void* d_out, int out_size, void* d_ws, size_t ws_size,
                              hipStream_t stream) {
    const float* x    = (const float*)d_in[0];
    const int*   ei   = (const int*)d_in[1];
    const float* ea   = (const float*)d_in[2];
    const float* emb  = (const float*)d_in[3];
    const float* w1q  = (const float*)d_in[4];  const float* b1q = (const float*)d_in[5];
    const float* w1k  = (const float*)d_in[6];  const float* b1k = (const float*)d_in[7];
    const float* w1v  = (const float*)d_in[8];  const float* b1v = (const float*)d_in[9];
    const float* w1e  = (const float*)d_in[10];
    const float* w1s  = (const float*)d_in[11]; const float* b1s = (const float*)d_in[12];
    const float* w2q  = (const float*)d_in[13]; const float* b2q = (const float*)d_in[14];
    const float* w2k  = (const float*)d_in[15]; const float* b2k = (const float*)d_in[16];
    const float* w2v  = (const float*)d_in[17]; const float* b2v = (const float*)d_in[18];
    const float* w2e  = (const float*)d_in[19];
    const float* w2s  = (const float*)d_in[20]; const float* b2s = (const float*)d_in[21];

    const int* srcI = ei;
    const int* dstI = ei + NE;

    float* Q = (float*)d_ws;                                        // N x 128 f32 (pre-scaled)
    unsigned short* KV = (unsigned short*)(Q + (size_t)NN * OUTF);  // N x 256 bf16 [K|V]
    float* H = (float*)(KV + (size_t)NN * 256);                     // N x 128 f32
    unsigned short* EE1 = (unsigned short*)(H + (size_t)NN * OUTF); // E x 128 bf16
    unsigned short* EE2 = EE1 + (size_t)NE * 128;                   // E x 128 bf16
    int* csr_src   = (int*)(EE2 + (size_t)NE * 128);
    int* csr_eid   = csr_src + NE;
    int* row_start = csr_eid + NE;            // N+1
    int* cursor    = row_start + NN + 1;
    int* cnt       = cursor + NN;
    int* S1        = cnt + NN;
    int* bsum      = S1 + NN;
    int* boff      = bsum + NSCANB;
    unsigned short* WT1  = (unsigned short*)(boff + NSCANB + 1);
    unsigned short* WT2  = WT1 + 512 * KPAD;
    unsigned short* WmT1 = WT2 + 512 * KPAD;
    unsigned short* WmT2 = WmT1 + OUTF * KPAD;
    float* bias1 = (float*)(WmT2 + OUTF * KPAD);
    float* bias2 = bias1 + 512;

    prep_weights<<<128, 256, 0, stream>>>(w1q, w1k, w1v, w1s, w2q, w2k, w2v, w2s,
                                          w1e, w2e, emb,
                                          b1q, b1k, b1v, b1s, b2q, b2k, b2v, b2s,
                                          WT1, WT2, WmT1, WmT2, bias1, bias2);
    hipMemsetAsync(cnt, 0, (size_t)NN * sizeof(int), stream);
    hist_kernel<<<NE / 256, 256, 0, stream>>>(dstI, cnt);
    scan1<<<NSCANB, 256, 0, stream>>>(cnt, S1, bsum);
    scan2<<<1, 512, 0, stream>>>(bsum, boff);
    scan3<<<NSCANB, 256, 0, stream>>>(S1, boff, cnt, row_start, cursor);
    scatter_csr<<<NE / 256, 256, 0, stream>>>(srcI, dstI, cursor, csr_src, csr_eid);

    int ngrid = ((NN + 127) / 128) * 4;   // 782 row-tiles x 4 col-blocks = 3128
    int egrid = NE / (64 * ETILES);       // 2000

    // ---- node features L1 + fused dual-layer edge GEMM (pipelined, barrier-free) ----
    node_mfma<<<ngrid, 256, 0, stream>>>(x, K1, K1, 0, NN, WT1, bias1, Q, KV, H);
    edge_mfma_fused<<<egrid, 256, 0, stream>>>(ea, WmT1, WmT2, EE1, EE2);
    attn_node<<<2048, 256, 0, stream>>>(Q, KV, EE1, row_start, csr_src, csr_eid, H, H);

    // ---- layer 2 ----
    node_mfma<<<ngrid, 256, 0, stream>>>(H, OUTF, OUTF, 1, NN, WT2, bias2, Q, KV, (float*)d_out);
    attn_node<<<2048, 256, 0, stream>>>(Q, KV, EE2, row_start, csr_src, csr_eid, (float*)d_out, (float*)d_out);
}

// Round 16
// 986.495 us; speedup vs baseline: 1.3733x; 1.0077x over previous
//
#include <hip/hip_runtime.h>

#define NN 100000
#define NE 640000
#define OUTF 128
#define K1 100
#define KE 118
#define KPAD 128
#define ASTR 136              // padded LDS row stride (ushorts)
#define ATT_SCALE 0.17677669529663687f
#define NSCANB 391            // ceil(NN/256)
#define ETILES 5              // tiles per edge block (NE/64/2000)

typedef __attribute__((ext_vector_type(8))) short short8;
typedef __attribute__((ext_vector_type(4))) float f32x4;

__device__ __forceinline__ unsigned short f2bf(float f) {
    unsigned u = __float_as_uint(f);
    u += 0x7FFFu + ((u >> 16) & 1u);   // RNE
    return (unsigned short)(u >> 16);
}
__device__ __forceinline__ float bf2f(unsigned short h) {
    return __uint_as_float(((unsigned)h) << 16);
}

// ---------- prep: transposed bf16 weights [col][k]; WmT rows 118-121 = one-hot etype tables ----------
__global__ void prep_weights(
    const float* __restrict__ w1q, const float* __restrict__ w1k,
    const float* __restrict__ w1v, const float* __restrict__ w1s,
    const float* __restrict__ w2q, const float* __restrict__ w2k,
    const float* __restrict__ w2v, const float* __restrict__ w2s,
    const float* __restrict__ we1, const float* __restrict__ we2,
    const float* __restrict__ emb,
    const float* __restrict__ b1q, const float* __restrict__ b1k,
    const float* __restrict__ b1v, const float* __restrict__ b1s,
    const float* __restrict__ b2q, const float* __restrict__ b2k,
    const float* __restrict__ b2v, const float* __restrict__ b2s,
    unsigned short* __restrict__ WT1, unsigned short* __restrict__ WT2,
    unsigned short* __restrict__ WmT1, unsigned short* __restrict__ WmT2,
    float* __restrict__ bias1, float* __restrict__ bias2)
{
    int idx = blockIdx.x * blockDim.x + threadIdx.x;
    int stride = gridDim.x * blockDim.x;
    for (int i = idx; i < 512 * KPAD; i += stride) {
        int col = i >> 7, k = i & 127;
        int which = col >> 7, c = col & 127;
        const float* s1 = (which == 0) ? w1q : (which == 1) ? w1k : (which == 2) ? w1v : w1s;
        const float* s2 = (which == 0) ? w2q : (which == 1) ? w2k : (which == 2) ? w2v : w2s;
        float v1 = (k < K1) ? s1[k * OUTF + c] : 0.f;
        float v2 = s2[k * OUTF + c];
        WT1[i] = f2bf(v1); WT2[i] = f2bf(v2);
    }
    for (int i = idx; i < OUTF * KPAD; i += stride) {
        int col = i >> 7, k = i & 127;
        float v1 = 0.f, v2 = 0.f;
        if (k < 3)                 { v1 = we1[k * OUTF + col];       v2 = we2[k * OUTF + col]; }
        else if (k >= 4 && k < KE) { v1 = we1[(k - 1) * OUTF + col]; v2 = we2[(k - 1) * OUTF + col]; }
        else if (k >= KE && k < KE + 4) {
            int t = k - KE;
            #pragma unroll
            for (int r = 0; r < 8; r++) {
                float ev = emb[t * 8 + r];
                v1 += ev * we1[(117 + r) * OUTF + col];
                v2 += ev * we2[(117 + r) * OUTF + col];
            }
        }
        WmT1[i] = f2bf(v1); WmT2[i] = f2bf(v2);
    }
    for (int i = idx; i < 512; i += stride) {
        int which = i >> 7, c = i & 127;
        const float* sb1 = (which == 0) ? b1q : (which == 1) ? b1k : (which == 2) ? b1v : b1s;
        const float* sb2 = (which == 0) ? b2q : (which == 1) ? b2k : (which == 2) ? b2v : b2s;
        bias1[i] = sb1[c]; bias2[i] = sb2[c];
    }
}

// ---------- CSR build ----------
__global__ void hist_kernel(const int* __restrict__ dstI, int* __restrict__ cnt) {
    int e = blockIdx.x * 256 + threadIdx.x;
    if (e < NE) atomicAdd(&cnt[dstI[e]], 1);
}
__global__ void scan1(const int* __restrict__ cnt, int* __restrict__ S1, int* __restrict__ bsum) {
    __shared__ int sd[256];
    int t = blockIdx.x * 256 + threadIdx.x;
    sd[threadIdx.x] = (t < NN) ? cnt[t] : 0;
    __syncthreads();
    for (int off = 1; off < 256; off <<= 1) {
        int x = (threadIdx.x >= off) ? sd[threadIdx.x - off] : 0;
        __syncthreads();
        sd[threadIdx.x] += x;
        __syncthreads();
    }
    if (t < NN) S1[t] = sd[threadIdx.x];
    if (threadIdx.x == 255) bsum[blockIdx.x] = sd[255];
}
__global__ void scan2(const int* __restrict__ bsum, int* __restrict__ boff) {
    __shared__ int sd[512];
    int t = threadIdx.x;
    sd[t] = (t < NSCANB) ? bsum[t] : 0;
    __syncthreads();
    for (int off = 1; off < 512; off <<= 1) {
        int x = (t >= off) ? sd[t - off] : 0;
        __syncthreads();
        sd[t] += x;
        __syncthreads();
    }
    if (t < NSCANB) boff[t] = (t == 0) ? 0 : sd[t - 1];
}
__global__ void scan3(const int* __restrict__ S1, const int* __restrict__ boff,
                      const int* __restrict__ cnt,
                      int* __restrict__ row_start, int* __restrict__ cursor) {
    int t = blockIdx.x * 256 + threadIdx.x;
    if (t < NN) {
        int incl = S1[t] + boff[t >> 8];
        row_start[t + 1] = incl;
        cursor[t] = incl - cnt[t];
        if (t == 0) row_start[0] = 0;
    }
}
__global__ void scatter_csr(const int* __restrict__ srcI, const int* __restrict__ dstI,
                            int* __restrict__ cursor,
                            int* __restrict__ csr_src, int* __restrict__ csr_eid) {
    int e = blockIdx.x * 256 + threadIdx.x;
    if (e < NE) {
        int j = atomicAdd(&cursor[dstI[e]], 1);
        csr_src[j] = srcI[e];
        csr_eid[j] = e;
    }
}

// ---------- node GEMM, one 128-col block per block: coalesced LDS-staged epilogue ----------
// grid = ngrid*4; blockIdx = rowtile*4 + nb. nb: 0=Q(f32, pre-scaled) 1=K(bf16) 2=V(bf16) 3=H(f32)
__global__ __launch_bounds__(256) void node_mfma(
    const float* __restrict__ X, int ldx, int Kdim, int relu, int n,
    const unsigned short* __restrict__ WT, const float* __restrict__ bias,
    float* __restrict__ Qp, unsigned short* __restrict__ KVp, float* __restrict__ Hp)
{
    __shared__ unsigned short Alds[128][ASTR];     // A tile; reused as output staging after MFMA
    int tid = threadIdx.x;
    int rowbase = (blockIdx.x >> 2) * 128;
    int nb = blockIdx.x & 3;

    for (int idx = tid; idx < 128 * 68; idx += 256) {
        int r = idx / 68, kv = idx % 68;
        int k = kv * 2;
        float2 v = make_float2(0.f, 0.f);
        int gr = rowbase + r;
        if (gr < n && k < Kdim) v = *(const float2*)(X + (size_t)gr * ldx + k);
        if (relu) { v.x = fmaxf(v.x, 0.f); v.y = fmaxf(v.y, 0.f); }
        unsigned pv = (unsigned)f2bf(v.x) | ((unsigned)f2bf(v.y) << 16);
        *(unsigned*)&Alds[r][k] = pv;
    }
    __syncthreads();

    int lane = tid & 63, wid = tid >> 6;
    int wm = wid >> 1, wn = wid & 1;
    int l15 = lane & 15, l4 = lane >> 4;

    f32x4 acc[4][4];
    #pragma unroll
    for (int mf = 0; mf < 4; mf++)
        #pragma unroll
        for (int nf = 0; nf < 4; nf++)
            acc[mf][nf] = (f32x4){0.f, 0.f, 0.f, 0.f};

    const unsigned short* wbase = WT + (size_t)(nb * 128 + wn * 64 + l15) * KPAD + l4 * 8;
    #pragma unroll
    for (int ks = 0; ks < 4; ks++) {
        short8 af[4], bfr[4];
        #pragma unroll
        for (int mf = 0; mf < 4; mf++)
            af[mf] = *(const short8*)&Alds[wm * 64 + mf * 16 + l15][ks * 32 + l4 * 8];
        #pragma unroll
        for (int nf = 0; nf < 4; nf++)
            bfr[nf] = *(const short8*)(wbase + (size_t)nf * 16 * KPAD + ks * 32);
        #pragma unroll
        for (int mf = 0; mf < 4; mf++)
            #pragma unroll
            for (int nf = 0; nf < 4; nf++)
                acc[mf][nf] = __builtin_amdgcn_mfma_f32_16x16x32_bf16(af[mf], bfr[nf], acc[mf][nf], 0, 0, 0);
    }
    __syncthreads();   // A tile dead; reuse LDS for output staging

    if (nb == 1 || nb == 2) {
        // --- bf16 K/V: one 128x128 ushort tile, uint4 stores (full 256B rows) ---
        #pragma unroll
        for (int nf = 0; nf < 4; nf++) {
            int col = wn * 64 + nf * 16 + l15;
            float bv = bias[nb * 128 + col];
            #pragma unroll
            for (int mf = 0; mf < 4; mf++)
                #pragma unroll
                for (int rr = 0; rr < 4; rr++)
                    Alds[wm * 64 + mf * 16 + l4 * 4 + rr][col] = f2bf(acc[mf][nf][rr] + bv);
        }
        __syncthreads();
        int off = (nb == 1) ? 0 : 128;
        #pragma unroll
        for (int it = 0; it < 8; it++) {
            int idx = it * 256 + tid;
            int row = idx >> 4, c8 = (idx & 15) * 8;
            if (rowbase + row < n) {
                uint4 v = *(const uint4*)&Alds[row][c8];
                *(uint4*)(KVp + (size_t)(rowbase + row) * 256 + off + c8) = v;
            }
        }
    } else {
        // --- f32 Q/H: two 64-col half tiles ([128][68] f32 == Alds footprint), float4 stores ---
        float* Yp = (nb == 0) ? Qp : Hp;
        float scale = (nb == 0) ? ATT_SCALE : 1.f;
        float (*Sf)[68] = (float (*)[68])Alds;
        #pragma unroll
        for (int h = 0; h < 2; h++) {
            if (wn == h) {
                #pragma unroll
                for (int nf = 0; nf < 4; nf++) {
                    int col = wn * 64 + nf * 16 + l15;
                    float bv = bias[nb * 128 + col];
                    #pragma unroll
                    for (int mf = 0; mf < 4; mf++)
                        #pragma unroll
                        for (int rr = 0; rr < 4; rr++)
                            Sf[wm * 64 + mf * 16 + l4 * 4 + rr][nf * 16 + l15] =
                                (acc[mf][nf][rr] + bv) * scale;
                }
            }
            __syncthreads();
            #pragma unroll
            for (int it = 0; it < 8; it++) {
                int idx = it * 256 + tid;
                int row = idx >> 4, c4 = (idx & 15) * 4;
                if (rowbase + row < n) {
                    float4 v = *(const float4*)&Sf[row][c4];
                    *(float4*)(Yp + (size_t)(rowbase + row) * OUTF + h * 64 + c4) = v;
                }
            }
            if (h == 0) __syncthreads();
        }
    }
}

// ---------- fused dual-layer edge GEMM: 5 tiles/block, prefetch converts in-flight to bf16 ----------
// Zero barriers. Only the 16-VGPR bf16 fragment (not 32-VGPR raw fp32) lives across layer 2.
__global__ __launch_bounds__(256) void edge_mfma_fused(
    const float* __restrict__ EA,
    const unsigned short* __restrict__ WmT1, const unsigned short* __restrict__ WmT2,
    unsigned short* __restrict__ EE1, unsigned short* __restrict__ EE2)
{
    __shared__ unsigned short Tlds[64][ASTR];   // transpose buffer (wave-private quadrants)
    int tid = threadIdx.x;
    int lane = tid & 63, w = tid >> 6;
    int l15 = lane & 15, l4 = lane >> 4;
    int rbase = w * 16;
    int tile0 = blockIdx.x * ETILES;

    // load a tile's fragment, converting fp32 -> bf16 in-flight (short fp32 live ranges)
    auto load_tile = [&](int tile, short8* af) {
        const float* rp = EA + (size_t)(tile * 64 + rbase + l15) * KE;
        float etf = rp[3];
        #pragma unroll
        for (int ks = 0; ks < 4; ks++) {
            int cbase = ks * 32 + l4 * 8;
            float2 t0 = make_float2(0.f, 0.f), t1 = t0, t2 = t0, t3 = t0;
            if (cbase + 2 <= KE) t0 = *(const float2*)(rp + cbase);
            if (cbase + 4 <= KE) t1 = *(const float2*)(rp + cbase + 2);
            if (cbase + 6 <= KE) t2 = *(const float2*)(rp + cbase + 4);
            if (cbase + 8 <= KE) t3 = *(const float2*)(rp + cbase + 6);
            float fv[8] = {t0.x, t0.y, t1.x, t1.y, t2.x, t2.y, t3.x, t3.y};
            #pragma unroll
            for (int j = 0; j < 8; j++) {
                int col = cbase + j;
                float v = (col == 3) ? 0.f : fv[j];    // col 3 = etype -> zero
                af[ks][j] = f2bf(v);
            }
        }
        int oh = KE + (int)etf;                        // one-hot col 118..121 (ks==3 chunk)
        #pragma unroll
        for (int j = 0; j < 8; j++) {
            int col = 96 + l4 * 8 + j;
            if (col == oh) af[3][j] = 0x3F80;          // bf16 1.0
        }
    };
    auto do_layer = [&](const unsigned short* __restrict__ WmT, unsigned short* __restrict__ EEc,
                        int e0, const short8* af) {
        f32x4 acc[8];
        #pragma unroll
        for (int nf = 0; nf < 8; nf++) acc[nf] = (f32x4){0.f, 0.f, 0.f, 0.f};

        #pragma unroll
        for (int ks = 0; ks < 4; ks++) {
            short8 bfr[8];
            #pragma unroll
            for (int nf = 0; nf < 8; nf++)
                bfr[nf] = *(const short8*)(WmT + (size_t)(nf * 16 + l15) * KPAD + ks * 32 + l4 * 8);
            #pragma unroll
            for (int nf = 0; nf < 8; nf++)
                acc[nf] = __builtin_amdgcn_mfma_f32_16x16x32_bf16(af[ks], bfr[nf], acc[nf], 0, 0, 0);
        }
        // wave-private transpose through own LDS rows (no barrier), coalesced linear store
        #pragma unroll
        for (int nf = 0; nf < 8; nf++)
            #pragma unroll
            for (int rr = 0; rr < 4; rr++)
                Tlds[rbase + l4 * 4 + rr][nf * 16 + l15] = f2bf(acc[nf][rr]);
        #pragma unroll
        for (int it = 0; it < 4; it++) {
            int t2 = it * 64 + lane;
            int rid = t2 >> 4, c8 = (t2 & 15) * 8;     // rid spans [0,16) over it=0..3
            uint4 v = *(const uint4*)&Tlds[rbase + rid][c8];
            *(uint4*)(EEc + ((size_t)(e0 + rbase + rid)) * 128 + c8) = v;
        }
    };

    short8 afA[4];
    load_tile(tile0, afA);

    #pragma unroll
    for (int t = 0; t < ETILES; t++) {
        int e0 = (tile0 + t) * 64;
        do_layer(WmT1, EE1, e0, afA);
        short8 afB[4];
        if (t + 1 < ETILES) load_tile(tile0 + t + 1, afB);   // loads in flight under layer 2
        do_layer(WmT2, EE2, e0, afA);
        if (t + 1 < ETILES) {
            afA[0] = afB[0]; afA[1] = afB[1]; afA[2] = afB[2]; afA[3] = afB[3];
        }
    }
}

// ---------- fused attn: one wave per dst, online softmax, 3-deep data pipeline, zero atomics ----------
__global__ __launch_bounds__(256) void attn_node(
    const float* __restrict__ Qp, const unsigned short* __restrict__ KVp,
    const unsigned short* __restrict__ EEc,
    const int* __restrict__ row_start, const int* __restrict__ csr_src,
    const int* __restrict__ csr_eid,
    const float* __restrict__ Hskip, float* __restrict__ Out)
{
    int lane = threadIdx.x & 63;
    int gw = (int)((blockIdx.x * (size_t)blockDim.x + threadIdx.x) >> 6);
    int nW = (gridDim.x * blockDim.x) >> 6;
    int c2 = lane * 2;

    for (int d = gw; d < NN; d += nW) {
        int rs = row_start[d], re = row_start[d + 1];
        float2 q = *(const float2*)(Qp + (size_t)d * OUTF + c2);
        float m = -3.4e38f, s = 0.f, a0 = 0.f, a1 = 0.f;

        int j0 = (rs < re) ? rs : 0;
        int jlast = (rs < re) ? re - 1 : 0;
        int j1 = (j0 + 1 <= jlast) ? j0 + 1 : jlast;
        int j2 = (j0 + 2 <= jlast) ? j0 + 2 : jlast;
        int sjA = csr_src[j0], ejA = csr_eid[j0];
        int sjB = csr_src[j1], ejB = csr_eid[j1];
        int sjC = csr_src[j2], ejC = csr_eid[j2];
        // 3-deep data: A = j, B = j+1, C = j+2
        unsigned kA = *(const unsigned*)(KVp + (size_t)sjA * 256 + c2);
        unsigned vA = *(const unsigned*)(KVp + (size_t)sjA * 256 + 128 + c2);
        unsigned eA = *(const unsigned*)(EEc + (size_t)ejA * 128 + c2);
        unsigned kB = *(const unsigned*)(KVp + (size_t)sjB * 256 + c2);
        unsigned vB = *(const unsigned*)(KVp + (size_t)sjB * 256 + 128 + c2);
        unsigned eB = *(const unsigned*)(EEc + (size_t)ejB * 128 + c2);

        for (int j = rs; j < re; j++) {
            // issue j+2's data (indices already resident), prefetch j+3's indices
            unsigned kC = *(const unsigned*)(KVp + (size_t)sjC * 256 + c2);
            unsigned vC = *(const unsigned*)(KVp + (size_t)sjC * 256 + 128 + c2);
            unsigned eC = *(const unsigned*)(EEc + (size_t)ejC * 128 + c2);
            int j3 = (j + 3 <= jlast) ? j + 3 : jlast;
            int sjD = csr_src[j3], ejD = csr_eid[j3];

            float e0 = bf2f((unsigned short)(eA & 0xFFFFu));
            float e1 = bf2f((unsigned short)(eA >> 16));
            float k0 = bf2f((unsigned short)(kA & 0xFFFFu));
            float k1 = bf2f((unsigned short)(kA >> 16));
            float v0 = bf2f((unsigned short)(vA & 0xFFFFu));
            float v1 = bf2f((unsigned short)(vA >> 16));

            float t = q.x * (k0 + e0) + q.y * (k1 + e1);
            t += __shfl_xor(t, 1); t += __shfl_xor(t, 2);
            t += __shfl_xor(t, 4); t += __shfl_xor(t, 8);
            float alpha = t;   // ATT_SCALE pre-folded into Q
            float mn = fmaxf(m, alpha);
            float r = __expf(m - mn);
            float p = __expf(alpha - mn);
            s = s * r + p;
            a0 = a0 * r + p * (v0 + e0);
            a1 = a1 * r + p * (v1 + e1);
            m = mn;
            // rotate pipeline
            kA = kB; vA = vB; eA = eB;
            kB = kC; vB = vC; eB = eC;
            sjC = sjD; ejC = ejD;
        }
        float inv = 1.f / (s + 1e-16f);
        float2 h = *(const float2*)(Hskip + (size_t)d * OUTF + c2);
        float2 o;
        o.x = a0 * inv + h.x;
        o.y = a1 * inv + h.y;
        *(float2*)(Out + (size_t)d * OUTF + c2) = o;
    }
}

extern "C" void kernel_launch(void* const* d_in, const int* in_sizes, int n_in,
                              void* d_out, int out_size, void* d_ws, size_t ws_size,
                              hipStream_t stream) {
    const float* x    = (const float*)d_in[0];
    const int*   ei   = (const int*)d_in[1];
    const float* ea   = (const float*)d_in[2];
    const float* emb  = (const float*)d_in[3];
    const float* w1q  = (const float*)d_in[4];  const float* b1q = (const float*)d_in[5];
    const float* w1k  = (const float*)d_in[6];  const float* b1k = (const float*)d_in[7];
    const float* w1v  = (const float*)d_in[8];  const float* b1v = (const float*)d_in[9];
    const float* w1e  = (const float*)d_in[10];
    const float* w1s  = (const float*)d_in[11]; const float* b1s = (const float*)d_in[12];
    const float* w2q  = (const float*)d_in[13]; const float* b2q = (const float*)d_in[14];
    const float* w2k  = (const float*)d_in[15]; const float* b2k = (const float*)d_in[16];
    const float* w2v  = (const float*)d_in[17]; const float* b2v = (const float*)d_in[18];
    const float* w2e  = (const float*)d_in[19];
    const float* w2s  = (const float*)d_in[20]; const float* b2s = (const float*)d_in[21];

    const int* srcI = ei;
    const int* dstI = ei + NE;

    float* Q = (float*)d_ws;                                        // N x 128 f32 (pre-scaled)
    unsigned short* KV = (unsigned short*)(Q + (size_t)NN * OUTF);  // N x 256 bf16 [K|V]
    float* H = (float*)(KV + (size_t)NN * 256);                     // N x 128 f32
    unsigned short* EE1 = (unsigned short*)(H + (size_t)NN * OUTF); // E x 128 bf16
    unsigned short* EE2 = EE1 + (size_t)NE * 128;                   // E x 128 bf16
    int* csr_src   = (int*)(EE2 + (size_t)NE * 128);
    int* csr_eid   = csr_src + NE;
    int* row_start = csr_eid + NE;            // N+1
    int* cursor    = row_start + NN + 1;
    int* cnt       = cursor + NN;
    int* S1        = cnt + NN;
    int* bsum      = S1 + NN;
    int* boff      = bsum + NSCANB;
    unsigned short* WT1  = (unsigned short*)(boff + NSCANB + 1);
    unsigned short* WT2  = WT1 + 512 * KPAD;
    unsigned short* WmT1 = WT2 + 512 * KPAD;
    unsigned short* WmT2 = WmT1 + OUTF * KPAD;
    float* bias1 = (float*)(WmT2 + OUTF * KPAD);
    float* bias2 = bias1 + 512;

    prep_weights<<<128, 256, 0, stream>>>(w1q, w1k, w1v, w1s, w2q, w2k, w2v, w2s,
                                          w1e, w2e, emb,
                                          b1q, b1k, b1v, b1s, b2q, b2k, b2v, b2s,
                                          WT1, WT2, WmT1, WmT2, bias1, bias2);
    hipMemsetAsync(cnt, 0, (size_t)NN * sizeof(int), stream);
    hist_kernel<<<NE / 256, 256, 0, stream>>>(dstI, cnt);
    scan1<<<NSCANB, 256, 0, stream>>>(cnt, S1, bsum);
    scan2<<<1, 512, 0, stream>>>(bsum, boff);
    scan3<<<NSCANB, 256, 0, stream>>>(S1, boff, cnt, row_start, cursor);
    scatter_csr<<<NE / 256, 256, 0, stream>>>(srcI, dstI, cursor, csr_src, csr_eid);

    int ngrid = ((NN + 127) / 128) * 4;   // 782 row-tiles x 4 col-blocks = 3128
    int egrid = NE / (64 * ETILES);       // 2000

    // ---- node features L1 + fused dual-layer edge GEMM (pipelined, barrier-free) ----
    node_mfma<<<ngrid, 256, 0, stream>>>(x, K1, K1, 0, NN, WT1, bias1, Q, KV, H);
    edge_mfma_fused<<<egrid, 256, 0, stream>>>(ea, WmT1, WmT2, EE1, EE2);
    attn_node<<<4096, 256, 0, stream>>>(Q, KV, EE1, row_start, csr_src, csr_eid, H, H);

    // ---- layer 2 ----
    node_mfma<<<ngrid, 256, 0, stream>>>(H, OUTF, OUTF, 1, NN, WT2, bias2, Q, KV, (float*)d_out);
    attn_node<<<4096, 256, 0, stream>>>(Q, KV, EE2, row_start, csr_src, csr_eid, (float*)d_out, (float*)d_out);
}